// Round 9
// baseline (137.383 us; speedup 1.0000x reference)
//
#include <hip/hip_runtime.h>

// BandSplit R9: banded-matrix formulation (R7/R8) with
//  - bs_setup: ONE kernel per band packs post'-frags to LDS, builds pre'^T
//    frags on the fly, composes A_k = pre'^T x post' via MFMA, atomicAdds
//    into banded Mf32, and computes the bias vector (packs fused away).
//  - bs_banded: depth-2 register-double-buffered B prefetch, t-fastest grid
//    (consecutive blocks share the chunk's Mb in L2; x streamed once).

#define K_BANDS 64
#define COUT_D  128
#define T_DIM   1024
#define B_DIM   4
#define F_DIM   1025
#define WPAD    112      // padded band width (W <= 112, verified R2-R8)
#define DINP    224      // 2*WPAD, channel-blocked j/i = c*112 + wi
#define NMT     14       // DINP/16 tiles
#define NKTC    4        // 128/32 compose-K tiles
#define CHUNK   128      // output f-bins per chunk
#define NCHUNK  9        // ceil(1025/128)
#define WIN     352      // 112 + 128 + 112 input window
#define K2      704      // 2*WIN
#define KT2     22       // K2/32
#define OC      256      // out cols per chunk (2ch x 128)
#define NCT     16       // OC/16
#define M_TILE  32       // rows per main block
#define SXLD    712      // s_x row stride (shorts): 356 dw %32=4 -> 2-way free

typedef __attribute__((ext_vector_type(8))) short bf16x8;
typedef __attribute__((ext_vector_type(4))) float f32x4;

__device__ __forceinline__ unsigned short f2bf(float f) {
    unsigned u = __builtin_bit_cast(unsigned, f);
    u += 0x7FFFu + ((u >> 16) & 1u);          // RNE
    return (unsigned short)(u >> 16);
}
__device__ __forceinline__ void st8(unsigned short* o, const unsigned short* v) {
    *(ushort4*)(o)     = make_ushort4(v[0], v[1], v[2], v[3]);
    *(ushort4*)(o + 4) = make_ushort4(v[4], v[5], v[6], v[7]);
}

struct alignas(4) f4u { float v[4]; };        // dword-aligned 16B load

// ---- setup: per band, pack post' frags to LDS, build pre'^T frags on the
// fly, MFMA-compose, atomicAdd into banded Mf; bias to bias_g.
__global__ __launch_bounds__(256) void bs_setup(
    const float* __restrict__ pre_w,  const float* __restrict__ post_w,
    const float* __restrict__ pre_b,  const float* __restrict__ post_b,
    const int*   __restrict__ idx,    const float* __restrict__ melw,
    const float* __restrict__ mask,   const float* __restrict__ ola,
    float* __restrict__ Mf, float* __restrict__ bias_g, int W, int din)
{
    __shared__ unsigned short s_post[NKTC * NMT * 64 * 8];   // 57,344 B
    __shared__ unsigned char  s_flag[DINP];

    const int k   = blockIdx.x;
    const int tid = threadIdx.x;
    const int f0  = idx[(size_t)k * W];

    if (tid < DINP) {
        const int cc = tid >= WPAD, wi = tid - cc * WPAD;
        s_flag[tid] = (wi < W) && (melw[k * W + wi] * mask[k * W + wi] != 0.f);
    }

    // fill s_post: element (o = kt*32+kg*8+e, i = ct*16+col), * sc(i)
    for (int q = tid; q < NKTC * NMT * 64; q += 256) {
        const int kt   = q / (NMT * 64);
        const int rem  = q - kt * (NMT * 64);
        const int ct   = rem >> 6, lane = rem & 63;
        const int col  = lane & 15, kg = lane >> 4;
        const int i    = ct * 16 + col;
        const int cc   = (i >= WPAD);
        const int wi   = i - cc * WPAD;
        float sc = 0.f;
        if (wi < W) {
            const float mw = melw[k * W + wi] * mask[k * W + wi];
            if (mw != 0.f) sc = 1.0f / ola[idx[k * W + wi]];
        }
        unsigned short v[8];
#pragma unroll
        for (int e = 0; e < 8; ++e) {
            const int o = kt * 32 + kg * 8 + e;
            const float f = (sc != 0.f)
                ? sc * post_w[((size_t)k * COUT_D + o) * din + 2 * wi + cc] : 0.f;
            v[e] = f2bf(f);
        }
        st8(&s_post[(size_t)q * 8], v);
    }
    __syncthreads();

    const int lane = tid & 63, wave = tid >> 6;
    const int col  = lane & 15, kg  = lane >> 4;
    const bf16x8* bp = (const bf16x8*)s_post;

    for (int mt = wave; mt < NMT; mt += 4) {
        // build a[kt] on the fly: (j = mt*16+col, o = kt*32+kg*8+e)
        const int jl = mt * 16 + col;
        const int cc2 = jl >= WPAD, wj = jl - cc2 * WPAD;
        float wt = 0.f;
        if (wj < W) wt = melw[k * W + wj] * mask[k * W + wj];
        bf16x8 a[NKTC];
#pragma unroll
        for (int kt = 0; kt < NKTC; ++kt) {
            bf16x8 av = (bf16x8){0, 0, 0, 0, 0, 0, 0, 0};
            if (wt != 0.f) {
                const int o = kt * 32 + kg * 8;
                const float* src = pre_w
                    + ((size_t)k * din + 2 * wj + cc2) * COUT_D + o;
                const f4u p0 = *(const f4u*)(src);
                const f4u p1 = *(const f4u*)(src + 4);
#pragma unroll
                for (int e = 0; e < 4; ++e) {
                    av[e]     = (short)f2bf(wt * p0.v[e]);
                    av[e + 4] = (short)f2bf(wt * p1.v[e]);
                }
            }
            a[kt] = av;
        }

        for (int nt = 0; nt < NMT; ++nt) {
            f32x4 acc = (f32x4){0.f, 0.f, 0.f, 0.f};
#pragma unroll
            for (int kt = 0; kt < NKTC; ++kt)
                acc = __builtin_amdgcn_mfma_f32_16x16x32_bf16(
                    a[kt], bp[(kt * NMT + nt) * 64 + lane], acc, 0, 0, 0);
            const int i_loc = nt * 16 + col;
            if (!s_flag[i_loc]) continue;
            const int c  = i_loc >= WPAD, wi = i_loc - c * WPAD;
            const int f  = f0 + wi;                // output bin
            const int ch = f >> 7, df = f & 127;
            const int lo = (ch << 7) - WPAD;
            const size_t colIdx = (size_t)(c * CHUNK + df);
#pragma unroll
            for (int reg = 0; reg < 4; ++reg) {
                const int j_loc = mt * 16 + kg * 4 + reg;
                if (!s_flag[j_loc]) continue;
                const int c2 = j_loc >= WPAD, wi2 = j_loc - c2 * WPAD;
                const int jj = f0 + wi2 - lo;      // in [1, 350]
                atomicAdd(Mf + ((size_t)ch * K2 + c2 * WIN + jj) * OC + colIdx,
                          acc[reg]);
            }
        }
    }

    // bias[(c,f)] += sc * (pre_b . post_w[:, i] + post_b[i])
    if (tid < DINP && s_flag[tid]) {
        const int c = tid >= WPAD, wi = tid - c * WPAD;
        const int f = idx[k * W + wi];
        float v = post_b[(size_t)k * din + 2 * wi + c];
        for (int o = 0; o < COUT_D; ++o)
            v += pre_b[k * COUT_D + o]
                 * post_w[((size_t)k * COUT_D + o) * din + 2 * wi + c];
        atomicAdd(bias_g + c * F_DIM + f, v / ola[f]);
    }
}

// ---- convert banded Mf32 -> bf16 B-frags: (chunk, kt, ct, lane, 8)
__global__ __launch_bounds__(256) void bs_mk_bf16(
    const float* __restrict__ Mf, unsigned short* __restrict__ Mb)
{
    const int chunk = blockIdx.x, kt = blockIdx.y;
    for (int q = threadIdx.x; q < NCT * 64; q += 256) {
        const int ct = q >> 6, lane = q & 63;
        const int col = lane & 15, kg = lane >> 4;
        unsigned short v[8];
#pragma unroll
        for (int e = 0; e < 8; ++e) {
            const int jp = kt * 32 + kg * 8 + e;
            v[e] = f2bf(Mf[((size_t)chunk * K2 + jp) * OC + ct * 16 + col]);
        }
        st8(Mb + ((((size_t)chunk * KT2 + kt) * NCT + ct) * 64 + lane) * 8, v);
    }
}

// ---- main: out_row = M . x_window + bias. Depth-2 B prefetch, plain stores.
__global__ __launch_bounds__(256, 3) void bs_banded(
    const float* __restrict__ x, const unsigned short* __restrict__ Mb,
    const float* __restrict__ bias_g, float* __restrict__ out)
{
    __shared__ unsigned short s_x[M_TILE][SXLD];

    const int chunk  = blockIdx.y;                // t-tile fastest (blockIdx.x)
    const int m_base = blockIdx.x * M_TILE;
    const int tid    = threadIdx.x;
    const int lo     = chunk * CHUNK - WPAD;      // may be negative / past end

    // stage raw x window -> bf16 LDS (OOB -> clamped addr, values killed by
    // zero M rows)
    for (int p = tid; p < M_TILE * 2 * 88; p += 256) {
        const int seg = p / 88, q = p - seg * 88;
        const int row = seg >> 1, c = seg & 1;
        const int m = m_base + row, b = m >> 10, t = m & 1023;
        const float* xr = x + ((size_t)(b * 2 + c) * T_DIM + t) * F_DIM;
        const int fl = lo + 4 * q;
        float v0, v1, v2, v3;
        if (fl >= 0 && fl + 4 <= F_DIM) {
            const f4u vv = *reinterpret_cast<const f4u*>(xr + fl);
            v0 = vv.v[0]; v1 = vv.v[1]; v2 = vv.v[2]; v3 = vv.v[3];
        } else {
            const int e0 = min(max(fl, 0),     F_DIM - 1);
            const int e1 = min(max(fl + 1, 0), F_DIM - 1);
            const int e2 = min(max(fl + 2, 0), F_DIM - 1);
            const int e3 = min(max(fl + 3, 0), F_DIM - 1);
            v0 = xr[e0]; v1 = xr[e1]; v2 = xr[e2]; v3 = xr[e3];
        }
        const unsigned w0 = (unsigned)f2bf(v0) | ((unsigned)f2bf(v1) << 16);
        const unsigned w1 = (unsigned)f2bf(v2) | ((unsigned)f2bf(v3) << 16);
        unsigned* d = (unsigned*)&s_x[row][c * WIN + 4 * q];
        d[0] = w0; d[1] = w1;
    }
    __syncthreads();

    const int lane = tid & 63, wave = tid >> 6;
    const int col  = lane & 15, kg  = lane >> 4;

    f32x4 acc[4][2];
#pragma unroll
    for (int ctl = 0; ctl < 4; ++ctl)
#pragma unroll
        for (int mf = 0; mf < 2; ++mf) acc[ctl][mf] = (f32x4){0.f, 0.f, 0.f, 0.f};

    const bf16x8* bp = (const bf16x8*)(Mb + (size_t)chunk * KT2 * NCT * 512);

    bf16x8 bufA[4], bufB[4];
#pragma unroll
    for (int ctl = 0; ctl < 4; ++ctl) {
        bufA[ctl] = bp[(size_t)(0 * NCT + wave * 4 + ctl) * 64 + lane];
        bufB[ctl] = bp[(size_t)(1 * NCT + wave * 4 + ctl) * 64 + lane];
    }

#pragma unroll
    for (int kt = 0; kt < KT2; kt += 2) {
        {   // even phase: consume bufA, reload for kt+2
            const bf16x8 a0 = *(const bf16x8*)&s_x[col][kt * 32 + kg * 8];
            const bf16x8 a1 = *(const bf16x8*)&s_x[16 + col][kt * 32 + kg * 8];
#pragma unroll
            for (int ctl = 0; ctl < 4; ++ctl) {
                acc[ctl][0] = __builtin_amdgcn_mfma_f32_16x16x32_bf16(
                    a0, bufA[ctl], acc[ctl][0], 0, 0, 0);
                acc[ctl][1] = __builtin_amdgcn_mfma_f32_16x16x32_bf16(
                    a1, bufA[ctl], acc[ctl][1], 0, 0, 0);
            }
            if (kt + 2 < KT2) {
#pragma unroll
                for (int ctl = 0; ctl < 4; ++ctl)
                    bufA[ctl] = bp[(size_t)((kt + 2) * NCT + wave * 4 + ctl) * 64 + lane];
            }
        }
        {   // odd phase: consume bufB, reload for kt+3
            const bf16x8 a0 = *(const bf16x8*)&s_x[col][(kt + 1) * 32 + kg * 8];
            const bf16x8 a1 = *(const bf16x8*)&s_x[16 + col][(kt + 1) * 32 + kg * 8];
#pragma unroll
            for (int ctl = 0; ctl < 4; ++ctl) {
                acc[ctl][0] = __builtin_amdgcn_mfma_f32_16x16x32_bf16(
                    a0, bufB[ctl], acc[ctl][0], 0, 0, 0);
                acc[ctl][1] = __builtin_amdgcn_mfma_f32_16x16x32_bf16(
                    a1, bufB[ctl], acc[ctl][1], 0, 0, 0);
            }
            if (kt + 3 < KT2) {
#pragma unroll
                for (int ctl = 0; ctl < 4; ++ctl)
                    bufB[ctl] = bp[(size_t)((kt + 3) * NCT + wave * 4 + ctl) * 64 + lane];
            }
        }
    }

    // epilogue: dense store + bias
    const int b  = m_base >> 10;
    const int t0 = m_base & 1023;
#pragma unroll
    for (int ctl = 0; ctl < 4; ++ctl) {
        const int i  = (wave * 4 + ctl) * 16 + col;
        const int c  = i >> 7, df = i & 127;
        const int f  = chunk * CHUNK + df;
        if (f >= F_DIM) continue;
        const float bv = bias_g[c * F_DIM + f];
        float* orow = out + ((size_t)(b * 2 + c) * T_DIM + t0) * F_DIM + f;
#pragma unroll
        for (int mf = 0; mf < 2; ++mf)
#pragma unroll
            for (int reg = 0; reg < 4; ++reg) {
                const int r = mf * 16 + kg * 4 + reg;
                orow[(size_t)r * F_DIM] = acc[ctl][mf][reg] + bv;
            }
    }
}

extern "C" void kernel_launch(void* const* d_in, const int* in_sizes, int n_in,
                              void* d_out, int out_size, void* d_ws, size_t ws_size,
                              hipStream_t stream) {
    const float* x      = (const float*)d_in[0];
    const float* pre_w  = (const float*)d_in[1];
    const float* pre_b  = (const float*)d_in[2];
    const float* post_w = (const float*)d_in[3];
    const float* post_b = (const float*)d_in[4];
    const int*   idx    = (const int*)d_in[5];
    const float* melw   = (const float*)d_in[6];
    const float* mask   = (const float*)d_in[7];
    const float* ola    = (const float*)d_in[8];
    float* out = (float*)d_out;

    const int W   = in_sizes[5] / K_BANDS;   // <= 112
    const int din = 2 * W;

    // workspace: Mf (banded f32) | bias | Mb (bf16 frags)
    const size_t mf_bytes   = (size_t)NCHUNK * K2 * OC * 4;          // 6,488,064
    const size_t bias_bytes = 8448;
    float*          Mf     = (float*)d_ws;
    float*          bias_g = (float*)((char*)d_ws + mf_bytes);
    unsigned short* Mb     = (unsigned short*)((char*)d_ws + mf_bytes + bias_bytes);

    hipMemsetAsync(d_ws, 0, mf_bytes + bias_bytes, stream);

    bs_setup<<<K_BANDS, 256, 0, stream>>>(pre_w, post_w, pre_b, post_b, idx,
                                          melw, mask, ola, Mf, bias_g, W, din);
    bs_mk_bf16<<<dim3(NCHUNK, KT2), 256, 0, stream>>>(Mf, Mb);

    bs_banded<<<dim3((B_DIM * T_DIM) / M_TILE, NCHUNK), 256, 0, stream>>>(
        x, Mb, bias_g, out);
}

// Round 10
// 105.783 us; speedup vs baseline: 1.2987x; 1.2987x over previous
//
#include <hip/hip_runtime.h>

// BandSplit R10 = R8 setup chain (parallel 896-block compose + small packs,
// measured ~10us) + R9 bs_banded (depth-2 reg prefetch, t-fastest grid,
// 3 blocks/CU). Banded-matrix formulation: out_row = M . x_window + bias.

#define K_BANDS 64
#define COUT_D  128
#define T_DIM   1024
#define B_DIM   4
#define F_DIM   1025
#define WPAD    112      // padded band width (W <= 112, verified R2-R9)
#define DINP    224      // 2*WPAD, channel-blocked j/i = c*112 + wi
#define NMT     14       // DINP/16 tiles
#define NKTC    4        // 128/32 compose-K tiles
#define CHUNK   128      // output f-bins per chunk
#define NCHUNK  9        // ceil(1025/128)
#define WIN     352      // 112 + 128 + 112 input window
#define K2      704      // 2*WIN
#define KT2     22       // K2/32
#define OC      256      // out cols per chunk (2ch x 128)
#define NCT     16       // OC/16
#define M_TILE  32       // rows per main block
#define SXLD    712      // s_x row stride (shorts): 356 dw %32=4 -> 2-way free

typedef __attribute__((ext_vector_type(8))) short bf16x8;
typedef __attribute__((ext_vector_type(4))) float f32x4;

__device__ __forceinline__ unsigned short f2bf(float f) {
    unsigned u = __builtin_bit_cast(unsigned, f);
    u += 0x7FFFu + ((u >> 16) & 1u);          // RNE
    return (unsigned short)(u >> 16);
}
__device__ __forceinline__ void st8(unsigned short* o, const unsigned short* v) {
    *(ushort4*)(o)     = make_ushort4(v[0], v[1], v[2], v[3]);
    *(ushort4*)(o + 4) = make_ushort4(v[4], v[5], v[6], v[7]);
}

struct alignas(4) f4u { float v[4]; };        // dword-aligned 16B load

// ---- pack pre'^T as MFMA A-frags: (k, kt over o, mt over j, lane, 8)
__global__ __launch_bounds__(256) void bs_pack_preT(
    const float* __restrict__ pre_w, const float* __restrict__ melw,
    const float* __restrict__ mask, unsigned short* __restrict__ dst,
    int W, int din)
{
    const int k = blockIdx.x, kt = blockIdx.y;
    for (int q = threadIdx.x; q < NMT * 64; q += 256) {
        const int mt = q >> 6, lane = q & 63;
        const int j  = mt * 16 + (lane & 15);
        const int kg = lane >> 4;
        const int cc = (j >= WPAD);
        const int wi = j - cc * WPAD;
        float wt = 0.f;
        if (wi < W) wt = melw[k * W + wi] * mask[k * W + wi];
        unsigned short v[8];
#pragma unroll
        for (int e = 0; e < 8; ++e) {
            const int o = kt * 32 + kg * 8 + e;
            const float f = (wt != 0.f)
                ? wt * pre_w[((size_t)k * din + (2 * wi + cc)) * COUT_D + o] : 0.f;
            v[e] = f2bf(f);
        }
        st8(dst + ((((size_t)k * NKTC + kt) * NMT + mt) * 64 + lane) * 8, v);
    }
}

// ---- pack post' as MFMA B-frags: (k, kt over o, ct over i, lane, 8), * sc(i)
__global__ __launch_bounds__(256) void bs_pack_post(
    const float* __restrict__ post_w, const int* __restrict__ idx,
    const float* __restrict__ melw, const float* __restrict__ mask,
    const float* __restrict__ ola, unsigned short* __restrict__ dst,
    int W, int din)
{
    const int k = blockIdx.x, kt = blockIdx.y;
    for (int q = threadIdx.x; q < NMT * 64; q += 256) {
        const int ct = q >> 6, lane = q & 63;
        const int col = lane & 15, kg = lane >> 4;
        const int i  = ct * 16 + col;
        const int cc = (i >= WPAD);
        const int wi = i - cc * WPAD;
        float sc = 0.f;
        if (wi < W) {
            const float mw = melw[k * W + wi] * mask[k * W + wi];
            if (mw != 0.f) sc = 1.0f / ola[idx[k * W + wi]];
        }
        unsigned short v[8];
#pragma unroll
        for (int e = 0; e < 8; ++e) {
            const int o = kt * 32 + kg * 8 + e;
            const float f = (sc != 0.f)
                ? sc * post_w[((size_t)k * COUT_D + o) * din + 2 * wi + cc] : 0.f;
            v[e] = f2bf(f);
        }
        st8(dst + ((((size_t)k * NKTC + kt) * NMT + ct) * 64 + lane) * 8, v);
    }
}

// ---- compose A_k = pre'^T x post' (224x224, K=128), atomicAdd into banded
// Mf32.  grid (K_BANDS, NMT): block owns one mt row; waves split nt.
__global__ __launch_bounds__(256) void bs_compose(
    const unsigned short* __restrict__ preT,
    const unsigned short* __restrict__ postP,
    const int* __restrict__ idx, const float* __restrict__ melw,
    const float* __restrict__ mask,
    float* __restrict__ Mf, int W)
{
    __shared__ unsigned char s_flag[DINP];
    const int k   = blockIdx.x;
    const int mt  = blockIdx.y;
    const int tid = threadIdx.x;
    const int f0  = idx[(size_t)k * W];

    if (tid < DINP) {
        const int cc = tid >= WPAD, wi = tid - cc * WPAD;
        s_flag[tid] = (wi < W) && (melw[k * W + wi] * mask[k * W + wi] != 0.f);
    }
    __syncthreads();

    const int lane = tid & 63, wave = tid >> 6;
    const int col  = lane & 15, kg  = lane >> 4;
    const bf16x8* ap = (const bf16x8*)(preT  + (size_t)k * NKTC * NMT * 512);
    const bf16x8* bp = (const bf16x8*)(postP + (size_t)k * NKTC * NMT * 512);

    bf16x8 a[NKTC];
#pragma unroll
    for (int kt = 0; kt < NKTC; ++kt) a[kt] = ap[(kt * NMT + mt) * 64 + lane];

    for (int nt = wave; nt < NMT; nt += 4) {
        f32x4 acc = (f32x4){0.f, 0.f, 0.f, 0.f};
#pragma unroll
        for (int kt = 0; kt < NKTC; ++kt)
            acc = __builtin_amdgcn_mfma_f32_16x16x32_bf16(
                a[kt], bp[(kt * NMT + nt) * 64 + lane], acc, 0, 0, 0);
        const int i_loc = nt * 16 + col;
        if (!s_flag[i_loc]) continue;
        const int c  = i_loc >= WPAD, wi = i_loc - c * WPAD;
        const int f  = f0 + wi;                // output bin
        const int ch = f >> 7, df = f & 127;
        const int lo = (ch << 7) - WPAD;
        const size_t colIdx = (size_t)(c * CHUNK + df);
#pragma unroll
        for (int reg = 0; reg < 4; ++reg) {
            const int j_loc = mt * 16 + kg * 4 + reg;
            if (!s_flag[j_loc]) continue;
            const int c2 = j_loc >= WPAD, wi2 = j_loc - c2 * WPAD;
            const int jj = f0 + wi2 - lo;      // in [1, 350]
            atomicAdd(Mf + ((size_t)ch * K2 + c2 * WIN + jj) * OC + colIdx,
                      acc[reg]);
        }
    }
}

// ---- bias[(c,f)] += sc * (pre_b . post_w[:, i] + post_b[i]) per band
__global__ __launch_bounds__(256) void bs_bias(
    const float* __restrict__ pre_b,  const float* __restrict__ post_w,
    const float* __restrict__ post_b, const int* __restrict__ idx,
    const float* __restrict__ melw,   const float* __restrict__ mask,
    const float* __restrict__ ola, float* __restrict__ bias_g,
    int W, int din)
{
    const int k   = blockIdx.x;
    const int tid = threadIdx.x;
    if (tid >= DINP) return;
    const int c = tid >= WPAD, wi = tid - c * WPAD;
    if (wi >= W) return;
    if (melw[k * W + wi] * mask[k * W + wi] == 0.f) return;
    const int f = idx[k * W + wi];
    float v = post_b[(size_t)k * din + 2 * wi + c];
    for (int o = 0; o < COUT_D; ++o)
        v += pre_b[k * COUT_D + o]
             * post_w[((size_t)k * COUT_D + o) * din + 2 * wi + c];
    atomicAdd(bias_g + c * F_DIM + f, v / ola[f]);
}

// ---- convert banded Mf32 -> bf16 B-frags: (chunk, kt, ct, lane, 8)
__global__ __launch_bounds__(256) void bs_mk_bf16(
    const float* __restrict__ Mf, unsigned short* __restrict__ Mb)
{
    const int chunk = blockIdx.x, kt = blockIdx.y;
    for (int q = threadIdx.x; q < NCT * 64; q += 256) {
        const int ct = q >> 6, lane = q & 63;
        const int col = lane & 15, kg = lane >> 4;
        unsigned short v[8];
#pragma unroll
        for (int e = 0; e < 8; ++e) {
            const int jp = kt * 32 + kg * 8 + e;
            v[e] = f2bf(Mf[((size_t)chunk * K2 + jp) * OC + ct * 16 + col]);
        }
        st8(Mb + ((((size_t)chunk * KT2 + kt) * NCT + ct) * 64 + lane) * 8, v);
    }
}

// ---- main: out_row = M . x_window + bias. Depth-2 B prefetch, plain stores.
__global__ __launch_bounds__(256, 3) void bs_banded(
    const float* __restrict__ x, const unsigned short* __restrict__ Mb,
    const float* __restrict__ bias_g, float* __restrict__ out)
{
    __shared__ unsigned short s_x[M_TILE][SXLD];

    const int chunk  = blockIdx.y;                // t-tile fastest (blockIdx.x)
    const int m_base = blockIdx.x * M_TILE;
    const int tid    = threadIdx.x;
    const int lo     = chunk * CHUNK - WPAD;      // may be negative / past end

    // stage raw x window -> bf16 LDS (OOB -> clamped addr, values killed by
    // zero M rows)
    for (int p = tid; p < M_TILE * 2 * 88; p += 256) {
        const int seg = p / 88, q = p - seg * 88;
        const int row = seg >> 1, c = seg & 1;
        const int m = m_base + row, b = m >> 10, t = m & 1023;
        const float* xr = x + ((size_t)(b * 2 + c) * T_DIM + t) * F_DIM;
        const int fl = lo + 4 * q;
        float v0, v1, v2, v3;
        if (fl >= 0 && fl + 4 <= F_DIM) {
            const f4u vv = *reinterpret_cast<const f4u*>(xr + fl);
            v0 = vv.v[0]; v1 = vv.v[1]; v2 = vv.v[2]; v3 = vv.v[3];
        } else {
            const int e0 = min(max(fl, 0),     F_DIM - 1);
            const int e1 = min(max(fl + 1, 0), F_DIM - 1);
            const int e2 = min(max(fl + 2, 0), F_DIM - 1);
            const int e3 = min(max(fl + 3, 0), F_DIM - 1);
            v0 = xr[e0]; v1 = xr[e1]; v2 = xr[e2]; v3 = xr[e3];
        }
        const unsigned w0 = (unsigned)f2bf(v0) | ((unsigned)f2bf(v1) << 16);
        const unsigned w1 = (unsigned)f2bf(v2) | ((unsigned)f2bf(v3) << 16);
        unsigned* d = (unsigned*)&s_x[row][c * WIN + 4 * q];
        d[0] = w0; d[1] = w1;
    }
    __syncthreads();

    const int lane = tid & 63, wave = tid >> 6;
    const int col  = lane & 15, kg  = lane >> 4;

    f32x4 acc[4][2];
#pragma unroll
    for (int ctl = 0; ctl < 4; ++ctl)
#pragma unroll
        for (int mf = 0; mf < 2; ++mf) acc[ctl][mf] = (f32x4){0.f, 0.f, 0.f, 0.f};

    const bf16x8* bp = (const bf16x8*)(Mb + (size_t)chunk * KT2 * NCT * 512);

    bf16x8 bufA[4], bufB[4];
#pragma unroll
    for (int ctl = 0; ctl < 4; ++ctl) {
        bufA[ctl] = bp[(size_t)(0 * NCT + wave * 4 + ctl) * 64 + lane];
        bufB[ctl] = bp[(size_t)(1 * NCT + wave * 4 + ctl) * 64 + lane];
    }

#pragma unroll
    for (int kt = 0; kt < KT2; kt += 2) {
        {   // even phase: consume bufA, reload for kt+2
            const bf16x8 a0 = *(const bf16x8*)&s_x[col][kt * 32 + kg * 8];
            const bf16x8 a1 = *(const bf16x8*)&s_x[16 + col][kt * 32 + kg * 8];
#pragma unroll
            for (int ctl = 0; ctl < 4; ++ctl) {
                acc[ctl][0] = __builtin_amdgcn_mfma_f32_16x16x32_bf16(
                    a0, bufA[ctl], acc[ctl][0], 0, 0, 0);
                acc[ctl][1] = __builtin_amdgcn_mfma_f32_16x16x32_bf16(
                    a1, bufA[ctl], acc[ctl][1], 0, 0, 0);
            }
            if (kt + 2 < KT2) {
#pragma unroll
                for (int ctl = 0; ctl < 4; ++ctl)
                    bufA[ctl] = bp[(size_t)((kt + 2) * NCT + wave * 4 + ctl) * 64 + lane];
            }
        }
        {   // odd phase: consume bufB, reload for kt+3
            const bf16x8 a0 = *(const bf16x8*)&s_x[col][(kt + 1) * 32 + kg * 8];
            const bf16x8 a1 = *(const bf16x8*)&s_x[16 + col][(kt + 1) * 32 + kg * 8];
#pragma unroll
            for (int ctl = 0; ctl < 4; ++ctl) {
                acc[ctl][0] = __builtin_amdgcn_mfma_f32_16x16x32_bf16(
                    a0, bufB[ctl], acc[ctl][0], 0, 0, 0);
                acc[ctl][1] = __builtin_amdgcn_mfma_f32_16x16x32_bf16(
                    a1, bufB[ctl], acc[ctl][1], 0, 0, 0);
            }
            if (kt + 3 < KT2) {
#pragma unroll
                for (int ctl = 0; ctl < 4; ++ctl)
                    bufB[ctl] = bp[(size_t)((kt + 3) * NCT + wave * 4 + ctl) * 64 + lane];
            }
        }
    }

    // epilogue: dense store + bias
    const int b  = m_base >> 10;
    const int t0 = m_base & 1023;
#pragma unroll
    for (int ctl = 0; ctl < 4; ++ctl) {
        const int i  = (wave * 4 + ctl) * 16 + col;
        const int c  = i >> 7, df = i & 127;
        const int f  = chunk * CHUNK + df;
        if (f >= F_DIM) continue;
        const float bv = bias_g[c * F_DIM + f];
        float* orow = out + ((size_t)(b * 2 + c) * T_DIM + t0) * F_DIM + f;
#pragma unroll
        for (int mf = 0; mf < 2; ++mf)
#pragma unroll
            for (int reg = 0; reg < 4; ++reg) {
                const int r = mf * 16 + kg * 4 + reg;
                orow[(size_t)r * F_DIM] = acc[ctl][mf][reg] + bv;
            }
    }
}

extern "C" void kernel_launch(void* const* d_in, const int* in_sizes, int n_in,
                              void* d_out, int out_size, void* d_ws, size_t ws_size,
                              hipStream_t stream) {
    const float* x      = (const float*)d_in[0];
    const float* pre_w  = (const float*)d_in[1];
    const float* pre_b  = (const float*)d_in[2];
    const float* post_w = (const float*)d_in[3];
    const float* post_b = (const float*)d_in[4];
    const int*   idx    = (const int*)d_in[5];
    const float* melw   = (const float*)d_in[6];
    const float* mask   = (const float*)d_in[7];
    const float* ola    = (const float*)d_in[8];
    float* out = (float*)d_out;

    const int W   = in_sizes[5] / K_BANDS;   // <= 112
    const int din = 2 * W;

    // workspace: Mf (banded f32) | bias | preT | postP | Mb
    const size_t mf_bytes   = (size_t)NCHUNK * K2 * OC * 4;          // 6,488,064
    const size_t bias_bytes = 8448;
    float*          Mf     = (float*)d_ws;
    float*          bias_g = (float*)((char*)d_ws + mf_bytes);
    unsigned short* preT   = (unsigned short*)((char*)d_ws + mf_bytes + bias_bytes);
    const size_t frag_bytes = (size_t)K_BANDS * NKTC * NMT * 64 * 8 * 2; // 3,670,016
    unsigned short* postP  = (unsigned short*)((char*)preT + frag_bytes);
    unsigned short* Mb     = (unsigned short*)((char*)postP + frag_bytes);

    hipMemsetAsync(d_ws, 0, mf_bytes + bias_bytes, stream);

    bs_pack_preT<<<dim3(K_BANDS, NKTC), 256, 0, stream>>>(pre_w, melw, mask,
                                                          preT, W, din);
    bs_pack_post<<<dim3(K_BANDS, NKTC), 256, 0, stream>>>(post_w, idx, melw,
                                                          mask, ola, postP,
                                                          W, din);
    bs_compose<<<dim3(K_BANDS, NMT), 256, 0, stream>>>(preT, postP, idx, melw,
                                                       mask, Mf, W);
    bs_bias<<<K_BANDS, 256, 0, stream>>>(pre_b, post_w, post_b, idx, melw,
                                         mask, ola, bias_g, W, din);
    bs_mk_bf16<<<dim3(NCHUNK, KT2), 256, 0, stream>>>(Mf, Mb);

    bs_banded<<<dim3((B_DIM * T_DIM) / M_TILE, NCHUNK), 256, 0, stream>>>(
        x, Mb, bias_g, out);
}

// Round 11
// 100.507 us; speedup vs baseline: 1.3669x; 1.0525x over previous
//
#include <hip/hip_runtime.h>

// BandSplit R11 = R10 + bs_banded latency hiding: depth-4 register B-prefetch
// (fully unrolled 22 phases, compile-time buffer indices) and depth-1 A
// (LDS) prefetch issued before each MFMA cluster. Packs fused into one kernel.

#define K_BANDS 64
#define COUT_D  128
#define T_DIM   1024
#define B_DIM   4
#define F_DIM   1025
#define WPAD    112      // padded band width (W <= 112, verified R2-R10)
#define DINP    224      // 2*WPAD, channel-blocked j/i = c*112 + wi
#define NMT     14       // DINP/16 tiles
#define NKTC    4        // 128/32 compose-K tiles
#define CHUNK   128      // output f-bins per chunk
#define NCHUNK  9        // ceil(1025/128)
#define WIN     352      // 112 + 128 + 112 input window
#define K2      704      // 2*WIN
#define KT2     22       // K2/32
#define OC      256      // out cols per chunk (2ch x 128)
#define NCT     16       // OC/16
#define M_TILE  32       // rows per main block
#define SXLD    712      // s_x row stride (shorts)

typedef __attribute__((ext_vector_type(8))) short bf16x8;
typedef __attribute__((ext_vector_type(4))) float f32x4;

__device__ __forceinline__ unsigned short f2bf(float f) {
    unsigned u = __builtin_bit_cast(unsigned, f);
    u += 0x7FFFu + ((u >> 16) & 1u);          // RNE
    return (unsigned short)(u >> 16);
}
__device__ __forceinline__ void st8(unsigned short* o, const unsigned short* v) {
    *(ushort4*)(o)     = make_ushort4(v[0], v[1], v[2], v[3]);
    *(ushort4*)(o + 4) = make_ushort4(v[4], v[5], v[6], v[7]);
}

struct alignas(4) f4u { float v[4]; };        // dword-aligned 16B load

// ---- fused packs: z=0 -> pre'^T A-frags; z=1 -> post' B-frags
__global__ __launch_bounds__(256) void bs_pack(
    const float* __restrict__ pre_w, const float* __restrict__ post_w,
    const int* __restrict__ idx, const float* __restrict__ melw,
    const float* __restrict__ mask, const float* __restrict__ ola,
    unsigned short* __restrict__ dstA, unsigned short* __restrict__ dstB,
    int W, int din)
{
    const int k = blockIdx.x, kt = blockIdx.y;
    if (blockIdx.z == 0) {
        for (int q = threadIdx.x; q < NMT * 64; q += 256) {
            const int mt = q >> 6, lane = q & 63;
            const int j  = mt * 16 + (lane & 15);
            const int kg = lane >> 4;
            const int cc = (j >= WPAD);
            const int wi = j - cc * WPAD;
            float wt = 0.f;
            if (wi < W) wt = melw[k * W + wi] * mask[k * W + wi];
            unsigned short v[8];
#pragma unroll
            for (int e = 0; e < 8; ++e) {
                const int o = kt * 32 + kg * 8 + e;
                const float f = (wt != 0.f)
                    ? wt * pre_w[((size_t)k * din + (2 * wi + cc)) * COUT_D + o] : 0.f;
                v[e] = f2bf(f);
            }
            st8(dstA + ((((size_t)k * NKTC + kt) * NMT + mt) * 64 + lane) * 8, v);
        }
    } else {
        for (int q = threadIdx.x; q < NMT * 64; q += 256) {
            const int ct = q >> 6, lane = q & 63;
            const int col = lane & 15, kg = lane >> 4;
            const int i  = ct * 16 + col;
            const int cc = (i >= WPAD);
            const int wi = i - cc * WPAD;
            float sc = 0.f;
            if (wi < W) {
                const float mw = melw[k * W + wi] * mask[k * W + wi];
                if (mw != 0.f) sc = 1.0f / ola[idx[k * W + wi]];
            }
            unsigned short v[8];
#pragma unroll
            for (int e = 0; e < 8; ++e) {
                const int o = kt * 32 + kg * 8 + e;
                const float f = (sc != 0.f)
                    ? sc * post_w[((size_t)k * COUT_D + o) * din + 2 * wi + cc] : 0.f;
                v[e] = f2bf(f);
            }
            st8(dstB + ((((size_t)k * NKTC + kt) * NMT + ct) * 64 + lane) * 8, v);
        }
    }
}

// ---- compose A_k = pre'^T x post' (224x224, K=128), atomicAdd into banded Mf
__global__ __launch_bounds__(256) void bs_compose(
    const unsigned short* __restrict__ preT,
    const unsigned short* __restrict__ postP,
    const int* __restrict__ idx, const float* __restrict__ melw,
    const float* __restrict__ mask,
    float* __restrict__ Mf, int W)
{
    __shared__ unsigned char s_flag[DINP];
    const int k   = blockIdx.x;
    const int mt  = blockIdx.y;
    const int tid = threadIdx.x;
    const int f0  = idx[(size_t)k * W];

    if (tid < DINP) {
        const int cc = tid >= WPAD, wi = tid - cc * WPAD;
        s_flag[tid] = (wi < W) && (melw[k * W + wi] * mask[k * W + wi] != 0.f);
    }
    __syncthreads();

    const int lane = tid & 63, wave = tid >> 6;
    const int col  = lane & 15, kg  = lane >> 4;
    const bf16x8* ap = (const bf16x8*)(preT  + (size_t)k * NKTC * NMT * 512);
    const bf16x8* bp = (const bf16x8*)(postP + (size_t)k * NKTC * NMT * 512);

    bf16x8 a[NKTC];
#pragma unroll
    for (int kt = 0; kt < NKTC; ++kt) a[kt] = ap[(kt * NMT + mt) * 64 + lane];

    for (int nt = wave; nt < NMT; nt += 4) {
        f32x4 acc = (f32x4){0.f, 0.f, 0.f, 0.f};
#pragma unroll
        for (int kt = 0; kt < NKTC; ++kt)
            acc = __builtin_amdgcn_mfma_f32_16x16x32_bf16(
                a[kt], bp[(kt * NMT + nt) * 64 + lane], acc, 0, 0, 0);
        const int i_loc = nt * 16 + col;
        if (!s_flag[i_loc]) continue;
        const int c  = i_loc >= WPAD, wi = i_loc - c * WPAD;
        const int f  = f0 + wi;                // output bin
        const int ch = f >> 7, df = f & 127;
        const int lo = (ch << 7) - WPAD;
        const size_t colIdx = (size_t)(c * CHUNK + df);
#pragma unroll
        for (int reg = 0; reg < 4; ++reg) {
            const int j_loc = mt * 16 + kg * 4 + reg;
            if (!s_flag[j_loc]) continue;
            const int c2 = j_loc >= WPAD, wi2 = j_loc - c2 * WPAD;
            const int jj = f0 + wi2 - lo;      // in [1, 350]
            atomicAdd(Mf + ((size_t)ch * K2 + c2 * WIN + jj) * OC + colIdx,
                      acc[reg]);
        }
    }
}

// ---- bias[(c,f)] += sc * (pre_b . post_w[:, i] + post_b[i]) per band
__global__ __launch_bounds__(256) void bs_bias(
    const float* __restrict__ pre_b,  const float* __restrict__ post_w,
    const float* __restrict__ post_b, const int* __restrict__ idx,
    const float* __restrict__ melw,   const float* __restrict__ mask,
    const float* __restrict__ ola, float* __restrict__ bias_g,
    int W, int din)
{
    const int k   = blockIdx.x;
    const int tid = threadIdx.x;
    if (tid >= DINP) return;
    const int c = tid >= WPAD, wi = tid - c * WPAD;
    if (wi >= W) return;
    if (melw[k * W + wi] * mask[k * W + wi] == 0.f) return;
    const int f = idx[k * W + wi];
    float v = post_b[(size_t)k * din + 2 * wi + c];
    for (int o = 0; o < COUT_D; ++o)
        v += pre_b[k * COUT_D + o]
             * post_w[((size_t)k * COUT_D + o) * din + 2 * wi + c];
    atomicAdd(bias_g + c * F_DIM + f, v / ola[f]);
}

// ---- convert banded Mf32 -> bf16 B-frags: (chunk, kt, ct, lane, 8)
__global__ __launch_bounds__(256) void bs_mk_bf16(
    const float* __restrict__ Mf, unsigned short* __restrict__ Mb)
{
    const int chunk = blockIdx.x, kt = blockIdx.y;
    for (int q = threadIdx.x; q < NCT * 64; q += 256) {
        const int ct = q >> 6, lane = q & 63;
        const int col = lane & 15, kg = lane >> 4;
        unsigned short v[8];
#pragma unroll
        for (int e = 0; e < 8; ++e) {
            const int jp = kt * 32 + kg * 8 + e;
            v[e] = f2bf(Mf[((size_t)chunk * K2 + jp) * OC + ct * 16 + col]);
        }
        st8(Mb + ((((size_t)chunk * KT2 + kt) * NCT + ct) * 64 + lane) * 8, v);
    }
}

// ---- main: out_row = M . x_window + bias.
// Depth-4 B prefetch + depth-1 A prefetch, fully unrolled 22 phases.
__global__ __launch_bounds__(256, 3) void bs_banded(
    const float* __restrict__ x, const unsigned short* __restrict__ Mb,
    const float* __restrict__ bias_g, float* __restrict__ out)
{
    __shared__ unsigned short s_x[M_TILE][SXLD];

    const int chunk  = blockIdx.y;                // t-tile fastest (blockIdx.x)
    const int m_base = blockIdx.x * M_TILE;
    const int tid    = threadIdx.x;
    const int lo     = chunk * CHUNK - WPAD;      // may be negative / past end

    for (int p = tid; p < M_TILE * 2 * 88; p += 256) {
        const int seg = p / 88, q = p - seg * 88;
        const int row = seg >> 1, c = seg & 1;
        const int m = m_base + row, b = m >> 10, t = m & 1023;
        const float* xr = x + ((size_t)(b * 2 + c) * T_DIM + t) * F_DIM;
        const int fl = lo + 4 * q;
        float v0, v1, v2, v3;
        if (fl >= 0 && fl + 4 <= F_DIM) {
            const f4u vv = *reinterpret_cast<const f4u*>(xr + fl);
            v0 = vv.v[0]; v1 = vv.v[1]; v2 = vv.v[2]; v3 = vv.v[3];
        } else {
            const int e0 = min(max(fl, 0),     F_DIM - 1);
            const int e1 = min(max(fl + 1, 0), F_DIM - 1);
            const int e2 = min(max(fl + 2, 0), F_DIM - 1);
            const int e3 = min(max(fl + 3, 0), F_DIM - 1);
            v0 = xr[e0]; v1 = xr[e1]; v2 = xr[e2]; v3 = xr[e3];
        }
        const unsigned w0 = (unsigned)f2bf(v0) | ((unsigned)f2bf(v1) << 16);
        const unsigned w1 = (unsigned)f2bf(v2) | ((unsigned)f2bf(v3) << 16);
        unsigned* d = (unsigned*)&s_x[row][c * WIN + 4 * q];
        d[0] = w0; d[1] = w1;
    }
    __syncthreads();

    const int lane = tid & 63, wave = tid >> 6;
    const int col  = lane & 15, kg  = lane >> 4;

    f32x4 acc[4][2];
#pragma unroll
    for (int ctl = 0; ctl < 4; ++ctl)
#pragma unroll
        for (int mf = 0; mf < 2; ++mf) acc[ctl][mf] = (f32x4){0.f, 0.f, 0.f, 0.f};

    const bf16x8* bp = (const bf16x8*)(Mb + (size_t)chunk * KT2 * NCT * 512);

    bf16x8 b0[4], b1[4], b2[4], b3[4];
#pragma unroll
    for (int ctl = 0; ctl < 4; ++ctl) {
        b0[ctl] = bp[(size_t)(0 * NCT + wave * 4 + ctl) * 64 + lane];
        b1[ctl] = bp[(size_t)(1 * NCT + wave * 4 + ctl) * 64 + lane];
        b2[ctl] = bp[(size_t)(2 * NCT + wave * 4 + ctl) * 64 + lane];
        b3[ctl] = bp[(size_t)(3 * NCT + wave * 4 + ctl) * 64 + lane];
    }
    bf16x8 aC0 = *(const bf16x8*)&s_x[col][kg * 8];
    bf16x8 aC1 = *(const bf16x8*)&s_x[16 + col][kg * 8];
    bf16x8 aN0, aN1;

#define PH(KT, BUF)                                                            \
    {                                                                          \
        if ((KT) + 1 < KT2) {                                                  \
            aN0 = *(const bf16x8*)&s_x[col][((KT) + 1) * 32 + kg * 8];         \
            aN1 = *(const bf16x8*)&s_x[16 + col][((KT) + 1) * 32 + kg * 8];    \
        }                                                                      \
        _Pragma("unroll")                                                      \
        for (int ctl = 0; ctl < 4; ++ctl) {                                    \
            acc[ctl][0] = __builtin_amdgcn_mfma_f32_16x16x32_bf16(             \
                aC0, BUF[ctl], acc[ctl][0], 0, 0, 0);                          \
            acc[ctl][1] = __builtin_amdgcn_mfma_f32_16x16x32_bf16(             \
                aC1, BUF[ctl], acc[ctl][1], 0, 0, 0);                          \
        }                                                                      \
        if ((KT) + 4 < KT2) {                                                  \
            _Pragma("unroll")                                                  \
            for (int ctl = 0; ctl < 4; ++ctl)                                  \
                BUF[ctl] = bp[(size_t)(((KT) + 4) * NCT + wave * 4 + ctl) * 64 \
                              + lane];                                         \
        }                                                                      \
        aC0 = aN0; aC1 = aN1;                                                  \
    }

    PH(0, b0)  PH(1, b1)  PH(2, b2)  PH(3, b3)
    PH(4, b0)  PH(5, b1)  PH(6, b2)  PH(7, b3)
    PH(8, b0)  PH(9, b1)  PH(10, b2) PH(11, b3)
    PH(12, b0) PH(13, b1) PH(14, b2) PH(15, b3)
    PH(16, b0) PH(17, b1) PH(18, b2) PH(19, b3)
    PH(20, b0) PH(21, b1)
#undef PH

    // epilogue: dense store + bias
    const int b  = m_base >> 10;
    const int t0 = m_base & 1023;
#pragma unroll
    for (int ctl = 0; ctl < 4; ++ctl) {
        const int i  = (wave * 4 + ctl) * 16 + col;
        const int c  = i >> 7, df = i & 127;
        const int f  = chunk * CHUNK + df;
        if (f >= F_DIM) continue;
        const float bv = bias_g[c * F_DIM + f];
        float* orow = out + ((size_t)(b * 2 + c) * T_DIM + t0) * F_DIM + f;
#pragma unroll
        for (int mf = 0; mf < 2; ++mf)
#pragma unroll
            for (int reg = 0; reg < 4; ++reg) {
                const int r = mf * 16 + kg * 4 + reg;
                orow[(size_t)r * F_DIM] = acc[ctl][mf][reg] + bv;
            }
    }
}

extern "C" void kernel_launch(void* const* d_in, const int* in_sizes, int n_in,
                              void* d_out, int out_size, void* d_ws, size_t ws_size,
                              hipStream_t stream) {
    const float* x      = (const float*)d_in[0];
    const float* pre_w  = (const float*)d_in[1];
    const float* pre_b  = (const float*)d_in[2];
    const float* post_w = (const float*)d_in[3];
    const float* post_b = (const float*)d_in[4];
    const int*   idx    = (const int*)d_in[5];
    const float* melw   = (const float*)d_in[6];
    const float* mask   = (const float*)d_in[7];
    const float* ola    = (const float*)d_in[8];
    float* out = (float*)d_out;

    const int W   = in_sizes[5] / K_BANDS;   // <= 112
    const int din = 2 * W;

    // workspace: Mf (banded f32) | bias | preT | postP | Mb
    const size_t mf_bytes   = (size_t)NCHUNK * K2 * OC * 4;          // 6,488,064
    const size_t bias_bytes = 8448;
    float*          Mf     = (float*)d_ws;
    float*          bias_g = (float*)((char*)d_ws + mf_bytes);
    unsigned short* preT   = (unsigned short*)((char*)d_ws + mf_bytes + bias_bytes);
    const size_t frag_bytes = (size_t)K_BANDS * NKTC * NMT * 64 * 8 * 2; // 3,670,016
    unsigned short* postP  = (unsigned short*)((char*)preT + frag_bytes);
    unsigned short* Mb     = (unsigned short*)((char*)postP + frag_bytes);

    hipMemsetAsync(d_ws, 0, mf_bytes + bias_bytes, stream);

    bs_pack<<<dim3(K_BANDS, NKTC, 2), 256, 0, stream>>>(pre_w, post_w, idx,
                                                        melw, mask, ola,
                                                        preT, postP, W, din);
    bs_compose<<<dim3(K_BANDS, NMT), 256, 0, stream>>>(preT, postP, idx, melw,
                                                       mask, Mf, W);
    bs_bias<<<K_BANDS, 256, 0, stream>>>(pre_b, post_w, post_b, idx, melw,
                                         mask, ola, bias_g, W, din);
    bs_mk_bf16<<<dim3(NCHUNK, KT2), 256, 0, stream>>>(Mf, Mb);

    bs_banded<<<dim3((B_DIM * T_DIM) / M_TILE, NCHUNK), 256, 0, stream>>>(
        x, Mb, bias_g, out);
}

// Round 12
// 84.949 us; speedup vs baseline: 1.6173x; 1.1831x over previous
//
#include <hip/hip_runtime.h>

// BandSplit R12 = R11 with bs_banded as 512-thread/8-wave blocks: same
// M_TILE=32 tile and 45.5KB LDS, but 24 resident waves/CU (was 12) —
// occupancy was the measured stall (R9/R11 ILP changes were null).

#define K_BANDS 64
#define COUT_D  128
#define T_DIM   1024
#define B_DIM   4
#define F_DIM   1025
#define WPAD    112      // padded band width (W <= 112, verified R2-R11)
#define DINP    224      // 2*WPAD, channel-blocked j/i = c*112 + wi
#define NMT     14       // DINP/16 tiles
#define NKTC    4        // 128/32 compose-K tiles
#define CHUNK   128      // output f-bins per chunk
#define NCHUNK  9        // ceil(1025/128)
#define WIN     352      // 112 + 128 + 112 input window
#define K2      704      // 2*WIN
#define KT2     22       // K2/32
#define OC      256      // out cols per chunk (2ch x 128)
#define NCT     16       // OC/16
#define M_TILE  32       // rows per main block
#define SXLD    712      // s_x row stride (shorts)

typedef __attribute__((ext_vector_type(8))) short bf16x8;
typedef __attribute__((ext_vector_type(4))) float f32x4;

__device__ __forceinline__ unsigned short f2bf(float f) {
    unsigned u = __builtin_bit_cast(unsigned, f);
    u += 0x7FFFu + ((u >> 16) & 1u);          // RNE
    return (unsigned short)(u >> 16);
}
__device__ __forceinline__ void st8(unsigned short* o, const unsigned short* v) {
    *(ushort4*)(o)     = make_ushort4(v[0], v[1], v[2], v[3]);
    *(ushort4*)(o + 4) = make_ushort4(v[4], v[5], v[6], v[7]);
}

struct alignas(4) f4u { float v[4]; };        // dword-aligned 16B load

// ---- fused packs: z=0 -> pre'^T A-frags; z=1 -> post' B-frags
__global__ __launch_bounds__(256) void bs_pack(
    const float* __restrict__ pre_w, const float* __restrict__ post_w,
    const int* __restrict__ idx, const float* __restrict__ melw,
    const float* __restrict__ mask, const float* __restrict__ ola,
    unsigned short* __restrict__ dstA, unsigned short* __restrict__ dstB,
    int W, int din)
{
    const int k = blockIdx.x, kt = blockIdx.y;
    if (blockIdx.z == 0) {
        for (int q = threadIdx.x; q < NMT * 64; q += 256) {
            const int mt = q >> 6, lane = q & 63;
            const int j  = mt * 16 + (lane & 15);
            const int kg = lane >> 4;
            const int cc = (j >= WPAD);
            const int wi = j - cc * WPAD;
            float wt = 0.f;
            if (wi < W) wt = melw[k * W + wi] * mask[k * W + wi];
            unsigned short v[8];
#pragma unroll
            for (int e = 0; e < 8; ++e) {
                const int o = kt * 32 + kg * 8 + e;
                const float f = (wt != 0.f)
                    ? wt * pre_w[((size_t)k * din + (2 * wi + cc)) * COUT_D + o] : 0.f;
                v[e] = f2bf(f);
            }
            st8(dstA + ((((size_t)k * NKTC + kt) * NMT + mt) * 64 + lane) * 8, v);
        }
    } else {
        for (int q = threadIdx.x; q < NMT * 64; q += 256) {
            const int ct = q >> 6, lane = q & 63;
            const int col = lane & 15, kg = lane >> 4;
            const int i  = ct * 16 + col;
            const int cc = (i >= WPAD);
            const int wi = i - cc * WPAD;
            float sc = 0.f;
            if (wi < W) {
                const float mw = melw[k * W + wi] * mask[k * W + wi];
                if (mw != 0.f) sc = 1.0f / ola[idx[k * W + wi]];
            }
            unsigned short v[8];
#pragma unroll
            for (int e = 0; e < 8; ++e) {
                const int o = kt * 32 + kg * 8 + e;
                const float f = (sc != 0.f)
                    ? sc * post_w[((size_t)k * COUT_D + o) * din + 2 * wi + cc] : 0.f;
                v[e] = f2bf(f);
            }
            st8(dstB + ((((size_t)k * NKTC + kt) * NMT + ct) * 64 + lane) * 8, v);
        }
    }
}

// ---- compose A_k = pre'^T x post' (224x224, K=128), atomicAdd into banded Mf
__global__ __launch_bounds__(256) void bs_compose(
    const unsigned short* __restrict__ preT,
    const unsigned short* __restrict__ postP,
    const int* __restrict__ idx, const float* __restrict__ melw,
    const float* __restrict__ mask,
    float* __restrict__ Mf, int W)
{
    __shared__ unsigned char s_flag[DINP];
    const int k   = blockIdx.x;
    const int mt  = blockIdx.y;
    const int tid = threadIdx.x;
    const int f0  = idx[(size_t)k * W];

    if (tid < DINP) {
        const int cc = tid >= WPAD, wi = tid - cc * WPAD;
        s_flag[tid] = (wi < W) && (melw[k * W + wi] * mask[k * W + wi] != 0.f);
    }
    __syncthreads();

    const int lane = tid & 63, wave = tid >> 6;
    const int col  = lane & 15, kg  = lane >> 4;
    const bf16x8* ap = (const bf16x8*)(preT  + (size_t)k * NKTC * NMT * 512);
    const bf16x8* bp = (const bf16x8*)(postP + (size_t)k * NKTC * NMT * 512);

    bf16x8 a[NKTC];
#pragma unroll
    for (int kt = 0; kt < NKTC; ++kt) a[kt] = ap[(kt * NMT + mt) * 64 + lane];

    for (int nt = wave; nt < NMT; nt += 4) {
        f32x4 acc = (f32x4){0.f, 0.f, 0.f, 0.f};
#pragma unroll
        for (int kt = 0; kt < NKTC; ++kt)
            acc = __builtin_amdgcn_mfma_f32_16x16x32_bf16(
                a[kt], bp[(kt * NMT + nt) * 64 + lane], acc, 0, 0, 0);
        const int i_loc = nt * 16 + col;
        if (!s_flag[i_loc]) continue;
        const int c  = i_loc >= WPAD, wi = i_loc - c * WPAD;
        const int f  = f0 + wi;                // output bin
        const int ch = f >> 7, df = f & 127;
        const int lo = (ch << 7) - WPAD;
        const size_t colIdx = (size_t)(c * CHUNK + df);
#pragma unroll
        for (int reg = 0; reg < 4; ++reg) {
            const int j_loc = mt * 16 + kg * 4 + reg;
            if (!s_flag[j_loc]) continue;
            const int c2 = j_loc >= WPAD, wi2 = j_loc - c2 * WPAD;
            const int jj = f0 + wi2 - lo;      // in [1, 350]
            atomicAdd(Mf + ((size_t)ch * K2 + c2 * WIN + jj) * OC + colIdx,
                      acc[reg]);
        }
    }
}

// ---- bias[(c,f)] += sc * (pre_b . post_w[:, i] + post_b[i]) per band
__global__ __launch_bounds__(256) void bs_bias(
    const float* __restrict__ pre_b,  const float* __restrict__ post_w,
    const float* __restrict__ post_b, const int* __restrict__ idx,
    const float* __restrict__ melw,   const float* __restrict__ mask,
    const float* __restrict__ ola, float* __restrict__ bias_g,
    int W, int din)
{
    const int k   = blockIdx.x;
    const int tid = threadIdx.x;
    if (tid >= DINP) return;
    const int c = tid >= WPAD, wi = tid - c * WPAD;
    if (wi >= W) return;
    if (melw[k * W + wi] * mask[k * W + wi] == 0.f) return;
    const int f = idx[k * W + wi];
    float v = post_b[(size_t)k * din + 2 * wi + c];
    for (int o = 0; o < COUT_D; ++o)
        v += pre_b[k * COUT_D + o]
             * post_w[((size_t)k * COUT_D + o) * din + 2 * wi + c];
    atomicAdd(bias_g + c * F_DIM + f, v / ola[f]);
}

// ---- convert banded Mf32 -> bf16 B-frags: (chunk, kt, ct, lane, 8)
__global__ __launch_bounds__(256) void bs_mk_bf16(
    const float* __restrict__ Mf, unsigned short* __restrict__ Mb)
{
    const int chunk = blockIdx.x, kt = blockIdx.y;
    for (int q = threadIdx.x; q < NCT * 64; q += 256) {
        const int ct = q >> 6, lane = q & 63;
        const int col = lane & 15, kg = lane >> 4;
        unsigned short v[8];
#pragma unroll
        for (int e = 0; e < 8; ++e) {
            const int jp = kt * 32 + kg * 8 + e;
            v[e] = f2bf(Mf[((size_t)chunk * K2 + jp) * OC + ct * 16 + col]);
        }
        st8(Mb + ((((size_t)chunk * KT2 + kt) * NCT + ct) * 64 + lane) * 8, v);
    }
}

// ---- main: out_row = M . x_window + bias.  8 waves/block (2 ct each),
// depth-4 B prefetch + depth-1 A prefetch, fully unrolled 22 phases.
__global__ __launch_bounds__(512, 6) void bs_banded(
    const float* __restrict__ x, const unsigned short* __restrict__ Mb,
    const float* __restrict__ bias_g, float* __restrict__ out)
{
    __shared__ unsigned short s_x[M_TILE][SXLD];

    const int chunk  = blockIdx.y;                // t-tile fastest (blockIdx.x)
    const int m_base = blockIdx.x * M_TILE;
    const int tid    = threadIdx.x;
    const int lo     = chunk * CHUNK - WPAD;      // may be negative / past end

    for (int p = tid; p < M_TILE * 2 * 88; p += 512) {
        const int seg = p / 88, q = p - seg * 88;
        const int row = seg >> 1, c = seg & 1;
        const int m = m_base + row, b = m >> 10, t = m & 1023;
        const float* xr = x + ((size_t)(b * 2 + c) * T_DIM + t) * F_DIM;
        const int fl = lo + 4 * q;
        float v0, v1, v2, v3;
        if (fl >= 0 && fl + 4 <= F_DIM) {
            const f4u vv = *reinterpret_cast<const f4u*>(xr + fl);
            v0 = vv.v[0]; v1 = vv.v[1]; v2 = vv.v[2]; v3 = vv.v[3];
        } else {
            const int e0 = min(max(fl, 0),     F_DIM - 1);
            const int e1 = min(max(fl + 1, 0), F_DIM - 1);
            const int e2 = min(max(fl + 2, 0), F_DIM - 1);
            const int e3 = min(max(fl + 3, 0), F_DIM - 1);
            v0 = xr[e0]; v1 = xr[e1]; v2 = xr[e2]; v3 = xr[e3];
        }
        const unsigned w0 = (unsigned)f2bf(v0) | ((unsigned)f2bf(v1) << 16);
        const unsigned w1 = (unsigned)f2bf(v2) | ((unsigned)f2bf(v3) << 16);
        unsigned* d = (unsigned*)&s_x[row][c * WIN + 4 * q];
        d[0] = w0; d[1] = w1;
    }
    __syncthreads();

    const int lane = tid & 63, wave = tid >> 6;   // wave in [0,8)
    const int col  = lane & 15, kg  = lane >> 4;

    f32x4 acc[2][2];
#pragma unroll
    for (int ctl = 0; ctl < 2; ++ctl)
#pragma unroll
        for (int mf = 0; mf < 2; ++mf) acc[ctl][mf] = (f32x4){0.f, 0.f, 0.f, 0.f};

    const bf16x8* bp = (const bf16x8*)(Mb + (size_t)chunk * KT2 * NCT * 512);

    bf16x8 b0[2], b1[2], b2[2], b3[2];
#pragma unroll
    for (int ctl = 0; ctl < 2; ++ctl) {
        b0[ctl] = bp[(size_t)(0 * NCT + wave * 2 + ctl) * 64 + lane];
        b1[ctl] = bp[(size_t)(1 * NCT + wave * 2 + ctl) * 64 + lane];
        b2[ctl] = bp[(size_t)(2 * NCT + wave * 2 + ctl) * 64 + lane];
        b3[ctl] = bp[(size_t)(3 * NCT + wave * 2 + ctl) * 64 + lane];
    }
    bf16x8 aC0 = *(const bf16x8*)&s_x[col][kg * 8];
    bf16x8 aC1 = *(const bf16x8*)&s_x[16 + col][kg * 8];
    bf16x8 aN0, aN1;

#define PH(KT, BUF)                                                            \
    {                                                                          \
        if ((KT) + 1 < KT2) {                                                  \
            aN0 = *(const bf16x8*)&s_x[col][((KT) + 1) * 32 + kg * 8];         \
            aN1 = *(const bf16x8*)&s_x[16 + col][((KT) + 1) * 32 + kg * 8];    \
        }                                                                      \
        _Pragma("unroll")                                                      \
        for (int ctl = 0; ctl < 2; ++ctl) {                                    \
            acc[ctl][0] = __builtin_amdgcn_mfma_f32_16x16x32_bf16(             \
                aC0, BUF[ctl], acc[ctl][0], 0, 0, 0);                          \
            acc[ctl][1] = __builtin_amdgcn_mfma_f32_16x16x32_bf16(             \
                aC1, BUF[ctl], acc[ctl][1], 0, 0, 0);                          \
        }                                                                      \
        if ((KT) + 4 < KT2) {                                                  \
            _Pragma("unroll")                                                  \
            for (int ctl = 0; ctl < 2; ++ctl)                                  \
                BUF[ctl] = bp[(size_t)(((KT) + 4) * NCT + wave * 2 + ctl) * 64 \
                              + lane];                                         \
        }                                                                      \
        aC0 = aN0; aC1 = aN1;                                                  \
    }

    PH(0, b0)  PH(1, b1)  PH(2, b2)  PH(3, b3)
    PH(4, b0)  PH(5, b1)  PH(6, b2)  PH(7, b3)
    PH(8, b0)  PH(9, b1)  PH(10, b2) PH(11, b3)
    PH(12, b0) PH(13, b1) PH(14, b2) PH(15, b3)
    PH(16, b0) PH(17, b1) PH(18, b2) PH(19, b3)
    PH(20, b0) PH(21, b1)
#undef PH

    // epilogue: dense store + bias
    const int b  = m_base >> 10;
    const int t0 = m_base & 1023;
#pragma unroll
    for (int ctl = 0; ctl < 2; ++ctl) {
        const int i  = (wave * 2 + ctl) * 16 + col;
        const int c  = i >> 7, df = i & 127;
        const int f  = chunk * CHUNK + df;
        if (f >= F_DIM) continue;
        const float bv = bias_g[c * F_DIM + f];
        float* orow = out + ((size_t)(b * 2 + c) * T_DIM + t0) * F_DIM + f;
#pragma unroll
        for (int mf = 0; mf < 2; ++mf)
#pragma unroll
            for (int reg = 0; reg < 4; ++reg) {
                const int r = mf * 16 + kg * 4 + reg;
                orow[(size_t)r * F_DIM] = acc[ctl][mf][reg] + bv;
            }
    }
}

extern "C" void kernel_launch(void* const* d_in, const int* in_sizes, int n_in,
                              void* d_out, int out_size, void* d_ws, size_t ws_size,
                              hipStream_t stream) {
    const float* x      = (const float*)d_in[0];
    const float* pre_w  = (const float*)d_in[1];
    const float* pre_b  = (const float*)d_in[2];
    const float* post_w = (const float*)d_in[3];
    const float* post_b = (const float*)d_in[4];
    const int*   idx    = (const int*)d_in[5];
    const float* melw   = (const float*)d_in[6];
    const float* mask   = (const float*)d_in[7];
    const float* ola    = (const float*)d_in[8];
    float* out = (float*)d_out;

    const int W   = in_sizes[5] / K_BANDS;   // <= 112
    const int din = 2 * W;

    // workspace: Mf (banded f32) | bias | preT | postP | Mb
    const size_t mf_bytes   = (size_t)NCHUNK * K2 * OC * 4;          // 6,488,064
    const size_t bias_bytes = 8448;
    float*          Mf     = (float*)d_ws;
    float*          bias_g = (float*)((char*)d_ws + mf_bytes);
    unsigned short* preT   = (unsigned short*)((char*)d_ws + mf_bytes + bias_bytes);
    const size_t frag_bytes = (size_t)K_BANDS * NKTC * NMT * 64 * 8 * 2; // 3,670,016
    unsigned short* postP  = (unsigned short*)((char*)preT + frag_bytes);
    unsigned short* Mb     = (unsigned short*)((char*)postP + frag_bytes);

    hipMemsetAsync(d_ws, 0, mf_bytes + bias_bytes, stream);

    bs_pack<<<dim3(K_BANDS, NKTC, 2), 256, 0, stream>>>(pre_w, post_w, idx,
                                                        melw, mask, ola,
                                                        preT, postP, W, din);
    bs_compose<<<dim3(K_BANDS, NMT), 256, 0, stream>>>(preT, postP, idx, melw,
                                                       mask, Mf, W);
    bs_bias<<<K_BANDS, 256, 0, stream>>>(pre_b, post_w, post_b, idx, melw,
                                         mask, ola, bias_g, W, din);
    bs_mk_bf16<<<dim3(NCHUNK, KT2), 256, 0, stream>>>(Mf, Mb);

    bs_banded<<<dim3((B_DIM * T_DIM) / M_TILE, NCHUNK), 512, 0, stream>>>(
        x, Mb, bias_g, out);
}

// Round 13
// 82.215 us; speedup vs baseline: 1.6710x; 1.0332x over previous
//
#include <hip/hip_runtime.h>

// BandSplit R13 = R12 +
//  (a) bs_banded: channel-split K-loop -> 23KB LDS -> 4 blocks x 8 waves =
//      32 waves/CU (occupancy was the proven lever: 24%->48% gave 68->51us).
//      Phases 0-10 consume c=0 window, re-stage, 11-21 consume c=1.
//  (b) setup chain 6 -> 4 dispatches: Mf/bias zeroing folded into bs_pack,
//      bias dot-product folded into bs_compose (mt==14 blocks).

#define K_BANDS 64
#define COUT_D  128
#define T_DIM   1024
#define B_DIM   4
#define F_DIM   1025
#define WPAD    112      // padded band width (W <= 112, verified R2-R12)
#define DINP    224      // 2*WPAD, channel-blocked j/i = c*112 + wi
#define NMT     14       // DINP/16 tiles
#define NKTC    4        // 128/32 compose-K tiles
#define CHUNK   128      // output f-bins per chunk
#define NCHUNK  9        // ceil(1025/128)
#define WIN     352      // 112 + 128 + 112 input window (= 11 * 32)
#define K2      704      // 2*WIN
#define KT2     22       // K2/32
#define OC      256      // out cols per chunk (2ch x 128)
#define NCT     16       // OC/16
#define M_TILE  32       // rows per main block
#define SXC     360      // s_xc row stride (shorts): 180 dw %32=20 -> spread

typedef __attribute__((ext_vector_type(8))) short bf16x8;
typedef __attribute__((ext_vector_type(4))) float f32x4;

__device__ __forceinline__ unsigned short f2bf(float f) {
    unsigned u = __builtin_bit_cast(unsigned, f);
    u += 0x7FFFu + ((u >> 16) & 1u);          // RNE
    return (unsigned short)(u >> 16);
}
__device__ __forceinline__ void st8(unsigned short* o, const unsigned short* v) {
    *(ushort4*)(o)     = make_ushort4(v[0], v[1], v[2], v[3]);
    *(ushort4*)(o + 4) = make_ushort4(v[4], v[5], v[6], v[7]);
}

struct alignas(4) f4u { float v[4]; };        // dword-aligned 16B load

// ---- prep: zero Mf+bias slice, then pack frags (z=0 preT, z=1 postP)
__global__ __launch_bounds__(256) void bs_prep(
    const float* __restrict__ pre_w, const float* __restrict__ post_w,
    const int* __restrict__ idx, const float* __restrict__ melw,
    const float* __restrict__ mask, const float* __restrict__ ola,
    unsigned short* __restrict__ dstA, unsigned short* __restrict__ dstB,
    float* __restrict__ zbase, int zcount, int W, int din)
{
    const int k = blockIdx.x, kt = blockIdx.y;
    // zero slice (512 blocks x 256 threads, coalesced grid-stride)
    {
        const int nblk = gridDim.x * gridDim.y * gridDim.z;
        const int bid  = (blockIdx.z * gridDim.y + blockIdx.y) * gridDim.x
                       + blockIdx.x;
        const int nthr = nblk * 256;
        for (int i = bid * 256 + threadIdx.x; i < zcount; i += nthr)
            zbase[i] = 0.f;
    }
    if (blockIdx.z == 0) {
        for (int q = threadIdx.x; q < NMT * 64; q += 256) {
            const int mt = q >> 6, lane = q & 63;
            const int j  = mt * 16 + (lane & 15);
            const int kg = lane >> 4;
            const int cc = (j >= WPAD);
            const int wi = j - cc * WPAD;
            float wt = 0.f;
            if (wi < W) wt = melw[k * W + wi] * mask[k * W + wi];
            unsigned short v[8];
#pragma unroll
            for (int e = 0; e < 8; ++e) {
                const int o = kt * 32 + kg * 8 + e;
                const float f = (wt != 0.f)
                    ? wt * pre_w[((size_t)k * din + (2 * wi + cc)) * COUT_D + o] : 0.f;
                v[e] = f2bf(f);
            }
            st8(dstA + ((((size_t)k * NKTC + kt) * NMT + mt) * 64 + lane) * 8, v);
        }
    } else {
        for (int q = threadIdx.x; q < NMT * 64; q += 256) {
            const int ct = q >> 6, lane = q & 63;
            const int col = lane & 15, kg = lane >> 4;
            const int i  = ct * 16 + col;
            const int cc = (i >= WPAD);
            const int wi = i - cc * WPAD;
            float sc = 0.f;
            if (wi < W) {
                const float mw = melw[k * W + wi] * mask[k * W + wi];
                if (mw != 0.f) sc = 1.0f / ola[idx[k * W + wi]];
            }
            unsigned short v[8];
#pragma unroll
            for (int e = 0; e < 8; ++e) {
                const int o = kt * 32 + kg * 8 + e;
                const float f = (sc != 0.f)
                    ? sc * post_w[((size_t)k * COUT_D + o) * din + 2 * wi + cc] : 0.f;
                v[e] = f2bf(f);
            }
            st8(dstB + ((((size_t)k * NKTC + kt) * NMT + ct) * 64 + lane) * 8, v);
        }
    }
}

// ---- compose A_k = pre'^T x post', atomicAdd into banded Mf.
// mt in [0,14): MFMA compose.  mt == 14: bias dot-product.
__global__ __launch_bounds__(256) void bs_compose(
    const unsigned short* __restrict__ preT,
    const unsigned short* __restrict__ postP,
    const float* __restrict__ pre_b,  const float* __restrict__ post_w,
    const float* __restrict__ post_b,
    const int* __restrict__ idx, const float* __restrict__ melw,
    const float* __restrict__ mask, const float* __restrict__ ola,
    float* __restrict__ Mf, float* __restrict__ bias_g, int W, int din)
{
    __shared__ unsigned char s_flag[DINP];
    const int k   = blockIdx.x;
    const int mt  = blockIdx.y;
    const int tid = threadIdx.x;
    const int f0  = idx[(size_t)k * W];

    if (mt == NMT) {          // bias block
        if (tid >= DINP) return;
        const int c = tid >= WPAD, wi = tid - c * WPAD;
        if (wi >= W) return;
        if (melw[k * W + wi] * mask[k * W + wi] == 0.f) return;
        const int f = idx[k * W + wi];
        float v = post_b[(size_t)k * din + 2 * wi + c];
        for (int o = 0; o < COUT_D; ++o)
            v += pre_b[k * COUT_D + o]
                 * post_w[((size_t)k * COUT_D + o) * din + 2 * wi + c];
        atomicAdd(bias_g + c * F_DIM + f, v / ola[f]);
        return;
    }

    if (tid < DINP) {
        const int cc = tid >= WPAD, wi = tid - cc * WPAD;
        s_flag[tid] = (wi < W) && (melw[k * W + wi] * mask[k * W + wi] != 0.f);
    }
    __syncthreads();

    const int lane = tid & 63, wave = tid >> 6;
    const int col  = lane & 15, kg  = lane >> 4;
    const bf16x8* ap = (const bf16x8*)(preT  + (size_t)k * NKTC * NMT * 512);
    const bf16x8* bp = (const bf16x8*)(postP + (size_t)k * NKTC * NMT * 512);

    bf16x8 a[NKTC];
#pragma unroll
    for (int kt = 0; kt < NKTC; ++kt) a[kt] = ap[(kt * NMT + mt) * 64 + lane];

    for (int nt = wave; nt < NMT; nt += 4) {
        f32x4 acc = (f32x4){0.f, 0.f, 0.f, 0.f};
#pragma unroll
        for (int kt = 0; kt < NKTC; ++kt)
            acc = __builtin_amdgcn_mfma_f32_16x16x32_bf16(
                a[kt], bp[(kt * NMT + nt) * 64 + lane], acc, 0, 0, 0);
        const int i_loc = nt * 16 + col;
        if (!s_flag[i_loc]) continue;
        const int c  = i_loc >= WPAD, wi = i_loc - c * WPAD;
        const int f  = f0 + wi;
        const int ch = f >> 7, df = f & 127;
        const int lo = (ch << 7) - WPAD;
        const size_t colIdx = (size_t)(c * CHUNK + df);
#pragma unroll
        for (int reg = 0; reg < 4; ++reg) {
            const int j_loc = mt * 16 + kg * 4 + reg;
            if (!s_flag[j_loc]) continue;
            const int c2 = j_loc >= WPAD, wi2 = j_loc - c2 * WPAD;
            const int jj = f0 + wi2 - lo;      // in [1, 350]
            atomicAdd(Mf + ((size_t)ch * K2 + c2 * WIN + jj) * OC + colIdx,
                      acc[reg]);
        }
    }
}

// ---- convert banded Mf32 -> bf16 B-frags: (chunk, kt, ct, lane, 8)
__global__ __launch_bounds__(256) void bs_mk_bf16(
    const float* __restrict__ Mf, unsigned short* __restrict__ Mb)
{
    const int chunk = blockIdx.x, kt = blockIdx.y;
    for (int q = threadIdx.x; q < NCT * 64; q += 256) {
        const int ct = q >> 6, lane = q & 63;
        const int col = lane & 15, kg = lane >> 4;
        unsigned short v[8];
#pragma unroll
        for (int e = 0; e < 8; ++e) {
            const int jp = kt * 32 + kg * 8 + e;
            v[e] = f2bf(Mf[((size_t)chunk * K2 + jp) * OC + ct * 16 + col]);
        }
        st8(Mb + ((((size_t)chunk * KT2 + kt) * NCT + ct) * 64 + lane) * 8, v);
    }
}

// ---- main: out_row = M . x_window + bias. Channel-split K-loop, 23KB LDS,
// 4 blocks x 8 waves per CU. Depth-4 B prefetch rotates across the re-stage.
__global__ __launch_bounds__(512, 8) void bs_banded(
    const float* __restrict__ x, const unsigned short* __restrict__ Mb,
    const float* __restrict__ bias_g, float* __restrict__ out)
{
    __shared__ unsigned short s_xc[M_TILE][SXC];

    const int chunk  = blockIdx.y;                // t-tile fastest
    const int m_base = blockIdx.x * M_TILE;
    const int tid    = threadIdx.x;
    const int lo     = chunk * CHUNK - WPAD;

    auto stage = [&](int C) {
        for (int p = tid; p < M_TILE * 88; p += 512) {
            const int row = p / 88, q = p - row * 88;
            const int m = m_base + row, b = m >> 10, t = m & 1023;
            const float* xr = x + ((size_t)(b * 2 + C) * T_DIM + t) * F_DIM;
            const int fl = lo + 4 * q;
            float v0, v1, v2, v3;
            if (fl >= 0 && fl + 4 <= F_DIM) {
                const f4u vv = *reinterpret_cast<const f4u*>(xr + fl);
                v0 = vv.v[0]; v1 = vv.v[1]; v2 = vv.v[2]; v3 = vv.v[3];
            } else {
                const int e0 = min(max(fl, 0),     F_DIM - 1);
                const int e1 = min(max(fl + 1, 0), F_DIM - 1);
                const int e2 = min(max(fl + 2, 0), F_DIM - 1);
                const int e3 = min(max(fl + 3, 0), F_DIM - 1);
                v0 = xr[e0]; v1 = xr[e1]; v2 = xr[e2]; v3 = xr[e3];
            }
            const unsigned w0 = (unsigned)f2bf(v0) | ((unsigned)f2bf(v1) << 16);
            const unsigned w1 = (unsigned)f2bf(v2) | ((unsigned)f2bf(v3) << 16);
            unsigned* d = (unsigned*)&s_xc[row][4 * q];
            d[0] = w0; d[1] = w1;
        }
    };

    const int lane = tid & 63, wave = tid >> 6;   // wave in [0,8)
    const int col  = lane & 15, kg  = lane >> 4;

    f32x4 acc[2][2];
#pragma unroll
    for (int ctl = 0; ctl < 2; ++ctl)
#pragma unroll
        for (int mf = 0; mf < 2; ++mf) acc[ctl][mf] = (f32x4){0.f, 0.f, 0.f, 0.f};

    const bf16x8* bp = (const bf16x8*)(Mb + (size_t)chunk * KT2 * NCT * 512);

    bf16x8 b0[2], b1[2], b2[2], b3[2];
#pragma unroll
    for (int ctl = 0; ctl < 2; ++ctl) {
        b0[ctl] = bp[(size_t)(0 * NCT + wave * 2 + ctl) * 64 + lane];
        b1[ctl] = bp[(size_t)(1 * NCT + wave * 2 + ctl) * 64 + lane];
        b2[ctl] = bp[(size_t)(2 * NCT + wave * 2 + ctl) * 64 + lane];
        b3[ctl] = bp[(size_t)(3 * NCT + wave * 2 + ctl) * 64 + lane];
    }

    stage(0);
    __syncthreads();

    bf16x8 aC0 = *(const bf16x8*)&s_xc[col][kg * 8];
    bf16x8 aC1 = *(const bf16x8*)&s_xc[16 + col][kg * 8];
    bf16x8 aN0, aN1;

    // LB: local base (0 for pass c=0, 352 for pass c=1); LAST: no A-prefetch
#define PH(KT, BUF, LB, LAST)                                                  \
    {                                                                          \
        if (!(LAST)) {                                                         \
            aN0 = *(const bf16x8*)&s_xc[col][((KT) + 1) * 32 - (LB) + kg * 8]; \
            aN1 = *(const bf16x8*)&s_xc[16 + col][((KT) + 1) * 32 - (LB)      \
                                                  + kg * 8];                   \
        }                                                                      \
        _Pragma("unroll")                                                      \
        for (int ctl = 0; ctl < 2; ++ctl) {                                    \
            acc[ctl][0] = __builtin_amdgcn_mfma_f32_16x16x32_bf16(             \
                aC0, BUF[ctl], acc[ctl][0], 0, 0, 0);                          \
            acc[ctl][1] = __builtin_amdgcn_mfma_f32_16x16x32_bf16(             \
                aC1, BUF[ctl], acc[ctl][1], 0, 0, 0);                          \
        }                                                                      \
        if ((KT) + 4 < KT2) {                                                  \
            _Pragma("unroll")                                                  \
            for (int ctl = 0; ctl < 2; ++ctl)                                  \
                BUF[ctl] = bp[(size_t)(((KT) + 4) * NCT + wave * 2 + ctl) * 64 \
                              + lane];                                         \
        }                                                                      \
        aC0 = aN0; aC1 = aN1;                                                  \
    }

    // pass c = 0: kt 0..10
    PH(0, b0, 0, false)  PH(1, b1, 0, false)  PH(2, b2, 0, false)
    PH(3, b3, 0, false)  PH(4, b0, 0, false)  PH(5, b1, 0, false)
    PH(6, b2, 0, false)  PH(7, b3, 0, false)  PH(8, b0, 0, false)
    PH(9, b1, 0, false)  PH(10, b2, 0, true)

    __syncthreads();                 // all pass-0 LDS reads complete
    stage(1);
    __syncthreads();

    aC0 = *(const bf16x8*)&s_xc[col][kg * 8];
    aC1 = *(const bf16x8*)&s_xc[16 + col][kg * 8];

    // pass c = 1: kt 11..21 (B-buffer rotation continues: 11 -> b3)
    PH(11, b3, 352, false) PH(12, b0, 352, false) PH(13, b1, 352, false)
    PH(14, b2, 352, false) PH(15, b3, 352, false) PH(16, b0, 352, false)
    PH(17, b1, 352, false) PH(18, b2, 352, false) PH(19, b3, 352, false)
    PH(20, b0, 352, false) PH(21, b1, 352, true)
#undef PH

    // epilogue: dense store + bias
    const int b  = m_base >> 10;
    const int t0 = m_base & 1023;
#pragma unroll
    for (int ctl = 0; ctl < 2; ++ctl) {
        const int i  = (wave * 2 + ctl) * 16 + col;
        const int c  = i >> 7, df = i & 127;
        const int f  = chunk * CHUNK + df;
        if (f >= F_DIM) continue;
        const float bv = bias_g[c * F_DIM + f];
        float* orow = out + ((size_t)(b * 2 + c) * T_DIM + t0) * F_DIM + f;
#pragma unroll
        for (int mf = 0; mf < 2; ++mf)
#pragma unroll
            for (int reg = 0; reg < 4; ++reg) {
                const int r = mf * 16 + kg * 4 + reg;
                orow[(size_t)r * F_DIM] = acc[ctl][mf][reg] + bv;
            }
    }
}

extern "C" void kernel_launch(void* const* d_in, const int* in_sizes, int n_in,
                              void* d_out, int out_size, void* d_ws, size_t ws_size,
                              hipStream_t stream) {
    const float* x      = (const float*)d_in[0];
    const float* pre_w  = (const float*)d_in[1];
    const float* pre_b  = (const float*)d_in[2];
    const float* post_w = (const float*)d_in[3];
    const float* post_b = (const float*)d_in[4];
    const int*   idx    = (const int*)d_in[5];
    const float* melw   = (const float*)d_in[6];
    const float* mask   = (const float*)d_in[7];
    const float* ola    = (const float*)d_in[8];
    float* out = (float*)d_out;

    const int W   = in_sizes[5] / K_BANDS;   // <= 112
    const int din = 2 * W;

    // workspace: Mf (banded f32) | bias | preT | postP | Mb
    const size_t mf_bytes   = (size_t)NCHUNK * K2 * OC * 4;          // 6,488,064
    const size_t bias_bytes = 8448;
    float*          Mf     = (float*)d_ws;
    float*          bias_g = (float*)((char*)d_ws + mf_bytes);
    unsigned short* preT   = (unsigned short*)((char*)d_ws + mf_bytes + bias_bytes);
    const size_t frag_bytes = (size_t)K_BANDS * NKTC * NMT * 64 * 8 * 2; // 3,670,016
    unsigned short* postP  = (unsigned short*)((char*)preT + frag_bytes);
    unsigned short* Mb     = (unsigned short*)((char*)postP + frag_bytes);

    const int zcount = (int)((mf_bytes + bias_bytes) / 4);

    bs_prep<<<dim3(K_BANDS, NKTC, 2), 256, 0, stream>>>(
        pre_w, post_w, idx, melw, mask, ola, preT, postP,
        (float*)d_ws, zcount, W, din);
    bs_compose<<<dim3(K_BANDS, NMT + 1), 256, 0, stream>>>(
        preT, postP, pre_b, post_w, post_b, idx, melw, mask, ola,
        Mf, bias_g, W, din);
    bs_mk_bf16<<<dim3(NCHUNK, KT2), 256, 0, stream>>>(Mf, Mb);

    bs_banded<<<dim3((B_DIM * T_DIM) / M_TILE, NCHUNK), 512, 0, stream>>>(
        x, Mb, bias_g, out);
}

// Round 14
// 78.022 us; speedup vs baseline: 1.7608x; 1.0537x over previous
//
#include <hip/hip_runtime.h>

// BandSplit R14 = R13 with ONE change: bs_banded __launch_bounds__(512,8) ->
// (512,6). R13's (512,8) forced VGPR 32, which evicted the depth-4 B-prefetch
// buffers (FETCH 33->58MB, 51->65us despite higher occupancy). (512,6) gave
// VGPR 40 + working prefetch in R12. Channel-split 23KB LDS retained.

#define K_BANDS 64
#define COUT_D  128
#define T_DIM   1024
#define B_DIM   4
#define F_DIM   1025
#define WPAD    112      // padded band width (W <= 112, verified R2-R13)
#define DINP    224      // 2*WPAD, channel-blocked j/i = c*112 + wi
#define NMT     14       // DINP/16 tiles
#define NKTC    4        // 128/32 compose-K tiles
#define CHUNK   128      // output f-bins per chunk
#define NCHUNK  9        // ceil(1025/128)
#define WIN     352      // 112 + 128 + 112 input window (= 11 * 32)
#define K2      704      // 2*WIN
#define KT2     22       // K2/32
#define OC      256      // out cols per chunk (2ch x 128)
#define NCT     16       // OC/16
#define M_TILE  32       // rows per main block
#define SXC     360      // s_xc row stride (shorts): 180 dw %32=20 -> spread

typedef __attribute__((ext_vector_type(8))) short bf16x8;
typedef __attribute__((ext_vector_type(4))) float f32x4;

__device__ __forceinline__ unsigned short f2bf(float f) {
    unsigned u = __builtin_bit_cast(unsigned, f);
    u += 0x7FFFu + ((u >> 16) & 1u);          // RNE
    return (unsigned short)(u >> 16);
}
__device__ __forceinline__ void st8(unsigned short* o, const unsigned short* v) {
    *(ushort4*)(o)     = make_ushort4(v[0], v[1], v[2], v[3]);
    *(ushort4*)(o + 4) = make_ushort4(v[4], v[5], v[6], v[7]);
}

struct alignas(4) f4u { float v[4]; };        // dword-aligned 16B load

// ---- prep: zero Mf+bias slice, then pack frags (z=0 preT, z=1 postP)
__global__ __launch_bounds__(256) void bs_prep(
    const float* __restrict__ pre_w, const float* __restrict__ post_w,
    const int* __restrict__ idx, const float* __restrict__ melw,
    const float* __restrict__ mask, const float* __restrict__ ola,
    unsigned short* __restrict__ dstA, unsigned short* __restrict__ dstB,
    float* __restrict__ zbase, int zcount, int W, int din)
{
    const int k = blockIdx.x, kt = blockIdx.y;
    // zero slice (512 blocks x 256 threads, coalesced grid-stride)
    {
        const int nblk = gridDim.x * gridDim.y * gridDim.z;
        const int bid  = (blockIdx.z * gridDim.y + blockIdx.y) * gridDim.x
                       + blockIdx.x;
        const int nthr = nblk * 256;
        for (int i = bid * 256 + threadIdx.x; i < zcount; i += nthr)
            zbase[i] = 0.f;
    }
    if (blockIdx.z == 0) {
        for (int q = threadIdx.x; q < NMT * 64; q += 256) {
            const int mt = q >> 6, lane = q & 63;
            const int j  = mt * 16 + (lane & 15);
            const int kg = lane >> 4;
            const int cc = (j >= WPAD);
            const int wi = j - cc * WPAD;
            float wt = 0.f;
            if (wi < W) wt = melw[k * W + wi] * mask[k * W + wi];
            unsigned short v[8];
#pragma unroll
            for (int e = 0; e < 8; ++e) {
                const int o = kt * 32 + kg * 8 + e;
                const float f = (wt != 0.f)
                    ? wt * pre_w[((size_t)k * din + (2 * wi + cc)) * COUT_D + o] : 0.f;
                v[e] = f2bf(f);
            }
            st8(dstA + ((((size_t)k * NKTC + kt) * NMT + mt) * 64 + lane) * 8, v);
        }
    } else {
        for (int q = threadIdx.x; q < NMT * 64; q += 256) {
            const int ct = q >> 6, lane = q & 63;
            const int col = lane & 15, kg = lane >> 4;
            const int i  = ct * 16 + col;
            const int cc = (i >= WPAD);
            const int wi = i - cc * WPAD;
            float sc = 0.f;
            if (wi < W) {
                const float mw = melw[k * W + wi] * mask[k * W + wi];
                if (mw != 0.f) sc = 1.0f / ola[idx[k * W + wi]];
            }
            unsigned short v[8];
#pragma unroll
            for (int e = 0; e < 8; ++e) {
                const int o = kt * 32 + kg * 8 + e;
                const float f = (sc != 0.f)
                    ? sc * post_w[((size_t)k * COUT_D + o) * din + 2 * wi + cc] : 0.f;
                v[e] = f2bf(f);
            }
            st8(dstB + ((((size_t)k * NKTC + kt) * NMT + ct) * 64 + lane) * 8, v);
        }
    }
}

// ---- compose A_k = pre'^T x post', atomicAdd into banded Mf.
// mt in [0,14): MFMA compose.  mt == 14: bias dot-product.
__global__ __launch_bounds__(256) void bs_compose(
    const unsigned short* __restrict__ preT,
    const unsigned short* __restrict__ postP,
    const float* __restrict__ pre_b,  const float* __restrict__ post_w,
    const float* __restrict__ post_b,
    const int* __restrict__ idx, const float* __restrict__ melw,
    const float* __restrict__ mask, const float* __restrict__ ola,
    float* __restrict__ Mf, float* __restrict__ bias_g, int W, int din)
{
    __shared__ unsigned char s_flag[DINP];
    const int k   = blockIdx.x;
    const int mt  = blockIdx.y;
    const int tid = threadIdx.x;
    const int f0  = idx[(size_t)k * W];

    if (mt == NMT) {          // bias block
        if (tid >= DINP) return;
        const int c = tid >= WPAD, wi = tid - c * WPAD;
        if (wi >= W) return;
        if (melw[k * W + wi] * mask[k * W + wi] == 0.f) return;
        const int f = idx[k * W + wi];
        float v = post_b[(size_t)k * din + 2 * wi + c];
        for (int o = 0; o < COUT_D; ++o)
            v += pre_b[k * COUT_D + o]
                 * post_w[((size_t)k * COUT_D + o) * din + 2 * wi + c];
        atomicAdd(bias_g + c * F_DIM + f, v / ola[f]);
        return;
    }

    if (tid < DINP) {
        const int cc = tid >= WPAD, wi = tid - cc * WPAD;
        s_flag[tid] = (wi < W) && (melw[k * W + wi] * mask[k * W + wi] != 0.f);
    }
    __syncthreads();

    const int lane = tid & 63, wave = tid >> 6;
    const int col  = lane & 15, kg  = lane >> 4;
    const bf16x8* ap = (const bf16x8*)(preT  + (size_t)k * NKTC * NMT * 512);
    const bf16x8* bp = (const bf16x8*)(postP + (size_t)k * NKTC * NMT * 512);

    bf16x8 a[NKTC];
#pragma unroll
    for (int kt = 0; kt < NKTC; ++kt) a[kt] = ap[(kt * NMT + mt) * 64 + lane];

    for (int nt = wave; nt < NMT; nt += 4) {
        f32x4 acc = (f32x4){0.f, 0.f, 0.f, 0.f};
#pragma unroll
        for (int kt = 0; kt < NKTC; ++kt)
            acc = __builtin_amdgcn_mfma_f32_16x16x32_bf16(
                a[kt], bp[(kt * NMT + nt) * 64 + lane], acc, 0, 0, 0);
        const int i_loc = nt * 16 + col;
        if (!s_flag[i_loc]) continue;
        const int c  = i_loc >= WPAD, wi = i_loc - c * WPAD;
        const int f  = f0 + wi;
        const int ch = f >> 7, df = f & 127;
        const int lo = (ch << 7) - WPAD;
        const size_t colIdx = (size_t)(c * CHUNK + df);
#pragma unroll
        for (int reg = 0; reg < 4; ++reg) {
            const int j_loc = mt * 16 + kg * 4 + reg;
            if (!s_flag[j_loc]) continue;
            const int c2 = j_loc >= WPAD, wi2 = j_loc - c2 * WPAD;
            const int jj = f0 + wi2 - lo;      // in [1, 350]
            atomicAdd(Mf + ((size_t)ch * K2 + c2 * WIN + jj) * OC + colIdx,
                      acc[reg]);
        }
    }
}

// ---- convert banded Mf32 -> bf16 B-frags: (chunk, kt, ct, lane, 8)
__global__ __launch_bounds__(256) void bs_mk_bf16(
    const float* __restrict__ Mf, unsigned short* __restrict__ Mb)
{
    const int chunk = blockIdx.x, kt = blockIdx.y;
    for (int q = threadIdx.x; q < NCT * 64; q += 256) {
        const int ct = q >> 6, lane = q & 63;
        const int col = lane & 15, kg = lane >> 4;
        unsigned short v[8];
#pragma unroll
        for (int e = 0; e < 8; ++e) {
            const int jp = kt * 32 + kg * 8 + e;
            v[e] = f2bf(Mf[((size_t)chunk * K2 + jp) * OC + ct * 16 + col]);
        }
        st8(Mb + ((((size_t)chunk * KT2 + kt) * NCT + ct) * 64 + lane) * 8, v);
    }
}

// ---- main: out_row = M . x_window + bias. Channel-split K-loop, 23KB LDS.
// (512,6): enough VGPR headroom for the depth-4 B prefetch (R12-proven).
__global__ __launch_bounds__(512, 6) void bs_banded(
    const float* __restrict__ x, const unsigned short* __restrict__ Mb,
    const float* __restrict__ bias_g, float* __restrict__ out)
{
    __shared__ unsigned short s_xc[M_TILE][SXC];

    const int chunk  = blockIdx.y;                // t-tile fastest
    const int m_base = blockIdx.x * M_TILE;
    const int tid    = threadIdx.x;
    const int lo     = chunk * CHUNK - WPAD;

    auto stage = [&](int C) {
        for (int p = tid; p < M_TILE * 88; p += 512) {
            const int row = p / 88, q = p - row * 88;
            const int m = m_base + row, b = m >> 10, t = m & 1023;
            const float* xr = x + ((size_t)(b * 2 + C) * T_DIM + t) * F_DIM;
            const int fl = lo + 4 * q;
            float v0, v1, v2, v3;
            if (fl >= 0 && fl + 4 <= F_DIM) {
                const f4u vv = *reinterpret_cast<const f4u*>(xr + fl);
                v0 = vv.v[0]; v1 = vv.v[1]; v2 = vv.v[2]; v3 = vv.v[3];
            } else {
                const int e0 = min(max(fl, 0),     F_DIM - 1);
                const int e1 = min(max(fl + 1, 0), F_DIM - 1);
                const int e2 = min(max(fl + 2, 0), F_DIM - 1);
                const int e3 = min(max(fl + 3, 0), F_DIM - 1);
                v0 = xr[e0]; v1 = xr[e1]; v2 = xr[e2]; v3 = xr[e3];
            }
            const unsigned w0 = (unsigned)f2bf(v0) | ((unsigned)f2bf(v1) << 16);
            const unsigned w1 = (unsigned)f2bf(v2) | ((unsigned)f2bf(v3) << 16);
            unsigned* d = (unsigned*)&s_xc[row][4 * q];
            d[0] = w0; d[1] = w1;
        }
    };

    const int lane = tid & 63, wave = tid >> 6;   // wave in [0,8)
    const int col  = lane & 15, kg  = lane >> 4;

    f32x4 acc[2][2];
#pragma unroll
    for (int ctl = 0; ctl < 2; ++ctl)
#pragma unroll
        for (int mf = 0; mf < 2; ++mf) acc[ctl][mf] = (f32x4){0.f, 0.f, 0.f, 0.f};

    const bf16x8* bp = (const bf16x8*)(Mb + (size_t)chunk * KT2 * NCT * 512);

    bf16x8 b0[2], b1[2], b2[2], b3[2];
#pragma unroll
    for (int ctl = 0; ctl < 2; ++ctl) {
        b0[ctl] = bp[(size_t)(0 * NCT + wave * 2 + ctl) * 64 + lane];
        b1[ctl] = bp[(size_t)(1 * NCT + wave * 2 + ctl) * 64 + lane];
        b2[ctl] = bp[(size_t)(2 * NCT + wave * 2 + ctl) * 64 + lane];
        b3[ctl] = bp[(size_t)(3 * NCT + wave * 2 + ctl) * 64 + lane];
    }

    stage(0);
    __syncthreads();

    bf16x8 aC0 = *(const bf16x8*)&s_xc[col][kg * 8];
    bf16x8 aC1 = *(const bf16x8*)&s_xc[16 + col][kg * 8];
    bf16x8 aN0, aN1;

    // LB: local base (0 for pass c=0, 352 for pass c=1); LAST: no A-prefetch
#define PH(KT, BUF, LB, LAST)                                                  \
    {                                                                          \
        if (!(LAST)) {                                                         \
            aN0 = *(const bf16x8*)&s_xc[col][((KT) + 1) * 32 - (LB) + kg * 8]; \
            aN1 = *(const bf16x8*)&s_xc[16 + col][((KT) + 1) * 32 - (LB)      \
                                                  + kg * 8];                   \
        }                                                                      \
        _Pragma("unroll")                                                      \
        for (int ctl = 0; ctl < 2; ++ctl) {                                    \
            acc[ctl][0] = __builtin_amdgcn_mfma_f32_16x16x32_bf16(             \
                aC0, BUF[ctl], acc[ctl][0], 0, 0, 0);                          \
            acc[ctl][1] = __builtin_amdgcn_mfma_f32_16x16x32_bf16(             \
                aC1, BUF[ctl], acc[ctl][1], 0, 0, 0);                          \
        }                                                                      \
        if ((KT) + 4 < KT2) {                                                  \
            _Pragma("unroll")                                                  \
            for (int ctl = 0; ctl < 2; ++ctl)                                  \
                BUF[ctl] = bp[(size_t)(((KT) + 4) * NCT + wave * 2 + ctl) * 64 \
                              + lane];                                         \
        }                                                                      \
        aC0 = aN0; aC1 = aN1;                                                  \
    }

    // pass c = 0: kt 0..10
    PH(0, b0, 0, false)  PH(1, b1, 0, false)  PH(2, b2, 0, false)
    PH(3, b3, 0, false)  PH(4, b0, 0, false)  PH(5, b1, 0, false)
    PH(6, b2, 0, false)  PH(7, b3, 0, false)  PH(8, b0, 0, false)
    PH(9, b1, 0, false)  PH(10, b2, 0, true)

    __syncthreads();                 // all pass-0 LDS reads complete
    stage(1);
    __syncthreads();

    aC0 = *(const bf16x8*)&s_xc[col][kg * 8];
    aC1 = *(const bf16x8*)&s_xc[16 + col][kg * 8];

    // pass c = 1: kt 11..21 (B-buffer rotation continues: 11 -> b3)
    PH(11, b3, 352, false) PH(12, b0, 352, false) PH(13, b1, 352, false)
    PH(14, b2, 352, false) PH(15, b3, 352, false) PH(16, b0, 352, false)
    PH(17, b1, 352, false) PH(18, b2, 352, false) PH(19, b3, 352, false)
    PH(20, b0, 352, false) PH(21, b1, 352, true)
#undef PH

    // epilogue: dense store + bias
    const int b  = m_base >> 10;
    const int t0 = m_base & 1023;
#pragma unroll
    for (int ctl = 0; ctl < 2; ++ctl) {
        const int i  = (wave * 2 + ctl) * 16 + col;
        const int c  = i >> 7, df = i & 127;
        const int f  = chunk * CHUNK + df;
        if (f >= F_DIM) continue;
        const float bv = bias_g[c * F_DIM + f];
        float* orow = out + ((size_t)(b * 2 + c) * T_DIM + t0) * F_DIM + f;
#pragma unroll
        for (int mf = 0; mf < 2; ++mf)
#pragma unroll
            for (int reg = 0; reg < 4; ++reg) {
                const int r = mf * 16 + kg * 4 + reg;
                orow[(size_t)r * F_DIM] = acc[ctl][mf][reg] + bv;
            }
    }
}

extern "C" void kernel_launch(void* const* d_in, const int* in_sizes, int n_in,
                              void* d_out, int out_size, void* d_ws, size_t ws_size,
                              hipStream_t stream) {
    const float* x      = (const float*)d_in[0];
    const float* pre_w  = (const float*)d_in[1];
    const float* pre_b  = (const float*)d_in[2];
    const float* post_w = (const float*)d_in[3];
    const float* post_b = (const float*)d_in[4];
    const int*   idx    = (const int*)d_in[5];
    const float* melw   = (const float*)d_in[6];
    const float* mask   = (const float*)d_in[7];
    const float* ola    = (const float*)d_in[8];
    float* out = (float*)d_out;

    const int W   = in_sizes[5] / K_BANDS;   // <= 112
    const int din = 2 * W;

    // workspace: Mf (banded f32) | bias | preT | postP | Mb
    const size_t mf_bytes   = (size_t)NCHUNK * K2 * OC * 4;          // 6,488,064
    const size_t bias_bytes = 8448;
    float*          Mf     = (float*)d_ws;
    float*          bias_g = (float*)((char*)d_ws + mf_bytes);
    unsigned short* preT   = (unsigned short*)((char*)d_ws + mf_bytes + bias_bytes);
    const size_t frag_bytes = (size_t)K_BANDS * NKTC * NMT * 64 * 8 * 2; // 3,670,016
    unsigned short* postP  = (unsigned short*)((char*)preT + frag_bytes);
    unsigned short* Mb     = (unsigned short*)((char*)postP + frag_bytes);

    const int zcount = (int)((mf_bytes + bias_bytes) / 4);

    bs_prep<<<dim3(K_BANDS, NKTC, 2), 256, 0, stream>>>(
        pre_w, post_w, idx, melw, mask, ola, preT, postP,
        (float*)d_ws, zcount, W, din);
    bs_compose<<<dim3(K_BANDS, NMT + 1), 256, 0, stream>>>(
        preT, postP, pre_b, post_w, post_b, idx, melw, mask, ola,
        Mf, bias_g, W, din);
    bs_mk_bf16<<<dim3(NCHUNK, KT2), 256, 0, stream>>>(Mf, Mb);

    bs_banded<<<dim3((B_DIM * T_DIM) / M_TILE, NCHUNK), 512, 0, stream>>>(
        x, Mb, bias_g, out);
}

// Round 15
// 74.192 us; speedup vs baseline: 1.8517x; 1.0516x over previous
//
#include <hip/hip_runtime.h>

// BandSplit R15: bs_banded reverted to R12's full-window single-stage form
// (channel-split A/B'd as a loss), widened to 1024 threads / 16 waves with
// 1 ct-column per wave -> 2 blocks x 16 waves = 32 waves/CU theoretical.
// Depth-4 register B-prefetch kept. Setup chain = R14 (3 dispatches).

#define K_BANDS 64
#define COUT_D  128
#define T_DIM   1024
#define B_DIM   4
#define F_DIM   1025
#define WPAD    112      // padded band width (W <= 112, verified R2-R14)
#define DINP    224      // 2*WPAD, channel-blocked j/i = c*112 + wi
#define NMT     14       // DINP/16 tiles
#define NKTC    4        // 128/32 compose-K tiles
#define CHUNK   128      // output f-bins per chunk
#define NCHUNK  9        // ceil(1025/128)
#define WIN     352      // 112 + 128 + 112 input window
#define K2      704      // 2*WIN
#define KT2     22       // K2/32
#define OC      256      // out cols per chunk (2ch x 128)
#define NCT     16       // OC/16
#define M_TILE  32       // rows per main block
#define SXLD    712      // s_x row stride (shorts)

typedef __attribute__((ext_vector_type(8))) short bf16x8;
typedef __attribute__((ext_vector_type(4))) float f32x4;

__device__ __forceinline__ unsigned short f2bf(float f) {
    unsigned u = __builtin_bit_cast(unsigned, f);
    u += 0x7FFFu + ((u >> 16) & 1u);          // RNE
    return (unsigned short)(u >> 16);
}
__device__ __forceinline__ void st8(unsigned short* o, const unsigned short* v) {
    *(ushort4*)(o)     = make_ushort4(v[0], v[1], v[2], v[3]);
    *(ushort4*)(o + 4) = make_ushort4(v[4], v[5], v[6], v[7]);
}

struct alignas(4) f4u { float v[4]; };        // dword-aligned 16B load

// ---- prep: zero Mf+bias slice, then pack frags (z=0 preT, z=1 postP)
__global__ __launch_bounds__(256) void bs_prep(
    const float* __restrict__ pre_w, const float* __restrict__ post_w,
    const int* __restrict__ idx, const float* __restrict__ melw,
    const float* __restrict__ mask, const float* __restrict__ ola,
    unsigned short* __restrict__ dstA, unsigned short* __restrict__ dstB,
    float* __restrict__ zbase, int zcount, int W, int din)
{
    const int k = blockIdx.x, kt = blockIdx.y;
    {
        const int nblk = gridDim.x * gridDim.y * gridDim.z;
        const int bid  = (blockIdx.z * gridDim.y + blockIdx.y) * gridDim.x
                       + blockIdx.x;
        const int nthr = nblk * 256;
        for (int i = bid * 256 + threadIdx.x; i < zcount; i += nthr)
            zbase[i] = 0.f;
    }
    if (blockIdx.z == 0) {
        for (int q = threadIdx.x; q < NMT * 64; q += 256) {
            const int mt = q >> 6, lane = q & 63;
            const int j  = mt * 16 + (lane & 15);
            const int kg = lane >> 4;
            const int cc = (j >= WPAD);
            const int wi = j - cc * WPAD;
            float wt = 0.f;
            if (wi < W) wt = melw[k * W + wi] * mask[k * W + wi];
            unsigned short v[8];
#pragma unroll
            for (int e = 0; e < 8; ++e) {
                const int o = kt * 32 + kg * 8 + e;
                const float f = (wt != 0.f)
                    ? wt * pre_w[((size_t)k * din + (2 * wi + cc)) * COUT_D + o] : 0.f;
                v[e] = f2bf(f);
            }
            st8(dstA + ((((size_t)k * NKTC + kt) * NMT + mt) * 64 + lane) * 8, v);
        }
    } else {
        for (int q = threadIdx.x; q < NMT * 64; q += 256) {
            const int ct = q >> 6, lane = q & 63;
            const int col = lane & 15, kg = lane >> 4;
            const int i  = ct * 16 + col;
            const int cc = (i >= WPAD);
            const int wi = i - cc * WPAD;
            float sc = 0.f;
            if (wi < W) {
                const float mw = melw[k * W + wi] * mask[k * W + wi];
                if (mw != 0.f) sc = 1.0f / ola[idx[k * W + wi]];
            }
            unsigned short v[8];
#pragma unroll
            for (int e = 0; e < 8; ++e) {
                const int o = kt * 32 + kg * 8 + e;
                const float f = (sc != 0.f)
                    ? sc * post_w[((size_t)k * COUT_D + o) * din + 2 * wi + cc] : 0.f;
                v[e] = f2bf(f);
            }
            st8(dstB + ((((size_t)k * NKTC + kt) * NMT + ct) * 64 + lane) * 8, v);
        }
    }
}

// ---- compose A_k = pre'^T x post', atomicAdd into banded Mf.
// mt in [0,14): MFMA compose.  mt == 14: bias dot-product.
__global__ __launch_bounds__(256) void bs_compose(
    const unsigned short* __restrict__ preT,
    const unsigned short* __restrict__ postP,
    const float* __restrict__ pre_b,  const float* __restrict__ post_w,
    const float* __restrict__ post_b,
    const int* __restrict__ idx, const float* __restrict__ melw,
    const float* __restrict__ mask, const float* __restrict__ ola,
    float* __restrict__ Mf, float* __restrict__ bias_g, int W, int din)
{
    __shared__ unsigned char s_flag[DINP];
    const int k   = blockIdx.x;
    const int mt  = blockIdx.y;
    const int tid = threadIdx.x;
    const int f0  = idx[(size_t)k * W];

    if (mt == NMT) {          // bias block
        if (tid >= DINP) return;
        const int c = tid >= WPAD, wi = tid - c * WPAD;
        if (wi >= W) return;
        if (melw[k * W + wi] * mask[k * W + wi] == 0.f) return;
        const int f = idx[k * W + wi];
        float v = post_b[(size_t)k * din + 2 * wi + c];
        for (int o = 0; o < COUT_D; ++o)
            v += pre_b[k * COUT_D + o]
                 * post_w[((size_t)k * COUT_D + o) * din + 2 * wi + c];
        atomicAdd(bias_g + c * F_DIM + f, v / ola[f]);
        return;
    }

    if (tid < DINP) {
        const int cc = tid >= WPAD, wi = tid - cc * WPAD;
        s_flag[tid] = (wi < W) && (melw[k * W + wi] * mask[k * W + wi] != 0.f);
    }
    __syncthreads();

    const int lane = tid & 63, wave = tid >> 6;
    const int col  = lane & 15, kg  = lane >> 4;
    const bf16x8* ap = (const bf16x8*)(preT  + (size_t)k * NKTC * NMT * 512);
    const bf16x8* bp = (const bf16x8*)(postP + (size_t)k * NKTC * NMT * 512);

    bf16x8 a[NKTC];
#pragma unroll
    for (int kt = 0; kt < NKTC; ++kt) a[kt] = ap[(kt * NMT + mt) * 64 + lane];

    for (int nt = wave; nt < NMT; nt += 4) {
        f32x4 acc = (f32x4){0.f, 0.f, 0.f, 0.f};
#pragma unroll
        for (int kt = 0; kt < NKTC; ++kt)
            acc = __builtin_amdgcn_mfma_f32_16x16x32_bf16(
                a[kt], bp[(kt * NMT + nt) * 64 + lane], acc, 0, 0, 0);
        const int i_loc = nt * 16 + col;
        if (!s_flag[i_loc]) continue;
        const int c  = i_loc >= WPAD, wi = i_loc - c * WPAD;
        const int f  = f0 + wi;
        const int ch = f >> 7, df = f & 127;
        const int lo = (ch << 7) - WPAD;
        const size_t colIdx = (size_t)(c * CHUNK + df);
#pragma unroll
        for (int reg = 0; reg < 4; ++reg) {
            const int j_loc = mt * 16 + kg * 4 + reg;
            if (!s_flag[j_loc]) continue;
            const int c2 = j_loc >= WPAD, wi2 = j_loc - c2 * WPAD;
            const int jj = f0 + wi2 - lo;      // in [1, 350]
            atomicAdd(Mf + ((size_t)ch * K2 + c2 * WIN + jj) * OC + colIdx,
                      acc[reg]);
        }
    }
}

// ---- convert banded Mf32 -> bf16 B-frags: (chunk, kt, ct, lane, 8)
__global__ __launch_bounds__(256) void bs_mk_bf16(
    const float* __restrict__ Mf, unsigned short* __restrict__ Mb)
{
    const int chunk = blockIdx.x, kt = blockIdx.y;
    for (int q = threadIdx.x; q < NCT * 64; q += 256) {
        const int ct = q >> 6, lane = q & 63;
        const int col = lane & 15, kg = lane >> 4;
        unsigned short v[8];
#pragma unroll
        for (int e = 0; e < 8; ++e) {
            const int jp = kt * 32 + kg * 8 + e;
            v[e] = f2bf(Mf[((size_t)chunk * K2 + jp) * OC + ct * 16 + col]);
        }
        st8(Mb + ((((size_t)chunk * KT2 + kt) * NCT + ct) * 64 + lane) * 8, v);
    }
}

// ---- main: out_row = M . x_window + bias. Full-window single-stage (R12),
// 1024 threads / 16 waves, 1 ct per wave, depth-4 B prefetch, depth-1 A.
__global__ __launch_bounds__(1024, 8) void bs_banded(
    const float* __restrict__ x, const unsigned short* __restrict__ Mb,
    const float* __restrict__ bias_g, float* __restrict__ out)
{
    __shared__ unsigned short s_x[M_TILE][SXLD];

    const int chunk  = blockIdx.y;                // t-tile fastest
    const int m_base = blockIdx.x * M_TILE;
    const int tid    = threadIdx.x;
    const int lo     = chunk * CHUNK - WPAD;

    for (int p = tid; p < M_TILE * 2 * 88; p += 1024) {
        const int seg = p / 88, q = p - seg * 88;
        const int row = seg >> 1, c = seg & 1;
        const int m = m_base + row, b = m >> 10, t = m & 1023;
        const float* xr = x + ((size_t)(b * 2 + c) * T_DIM + t) * F_DIM;
        const int fl = lo + 4 * q;
        float v0, v1, v2, v3;
        if (fl >= 0 && fl + 4 <= F_DIM) {
            const f4u vv = *reinterpret_cast<const f4u*>(xr + fl);
            v0 = vv.v[0]; v1 = vv.v[1]; v2 = vv.v[2]; v3 = vv.v[3];
        } else {
            const int e0 = min(max(fl, 0),     F_DIM - 1);
            const int e1 = min(max(fl + 1, 0), F_DIM - 1);
            const int e2 = min(max(fl + 2, 0), F_DIM - 1);
            const int e3 = min(max(fl + 3, 0), F_DIM - 1);
            v0 = xr[e0]; v1 = xr[e1]; v2 = xr[e2]; v3 = xr[e3];
        }
        const unsigned w0 = (unsigned)f2bf(v0) | ((unsigned)f2bf(v1) << 16);
        const unsigned w1 = (unsigned)f2bf(v2) | ((unsigned)f2bf(v3) << 16);
        unsigned* d = (unsigned*)&s_x[row][c * WIN + 4 * q];
        d[0] = w0; d[1] = w1;
    }
    __syncthreads();

    const int lane = tid & 63, wave = tid >> 6;   // wave in [0,16) = ct
    const int col  = lane & 15, kg  = lane >> 4;

    f32x4 acc[2];
#pragma unroll
    for (int mf = 0; mf < 2; ++mf) acc[mf] = (f32x4){0.f, 0.f, 0.f, 0.f};

    const bf16x8* bp = (const bf16x8*)(Mb + (size_t)chunk * KT2 * NCT * 512);

    bf16x8 b0, b1, b2, b3;
    b0 = bp[(size_t)(0 * NCT + wave) * 64 + lane];
    b1 = bp[(size_t)(1 * NCT + wave) * 64 + lane];
    b2 = bp[(size_t)(2 * NCT + wave) * 64 + lane];
    b3 = bp[(size_t)(3 * NCT + wave) * 64 + lane];

    bf16x8 aC0 = *(const bf16x8*)&s_x[col][kg * 8];
    bf16x8 aC1 = *(const bf16x8*)&s_x[16 + col][kg * 8];
    bf16x8 aN0, aN1;

#define PH(KT, BUF)                                                            \
    {                                                                          \
        if ((KT) + 1 < KT2) {                                                  \
            aN0 = *(const bf16x8*)&s_x[col][((KT) + 1) * 32 + kg * 8];         \
            aN1 = *(const bf16x8*)&s_x[16 + col][((KT) + 1) * 32 + kg * 8];    \
        }                                                                      \
        acc[0] = __builtin_amdgcn_mfma_f32_16x16x32_bf16(                      \
            aC0, BUF, acc[0], 0, 0, 0);                                        \
        acc[1] = __builtin_amdgcn_mfma_f32_16x16x32_bf16(                      \
            aC1, BUF, acc[1], 0, 0, 0);                                        \
        if ((KT) + 4 < KT2) {                                                  \
            BUF = bp[(size_t)(((KT) + 4) * NCT + wave) * 64 + lane];           \
        }                                                                      \
        aC0 = aN0; aC1 = aN1;                                                  \
    }

    PH(0, b0)  PH(1, b1)  PH(2, b2)  PH(3, b3)
    PH(4, b0)  PH(5, b1)  PH(6, b2)  PH(7, b3)
    PH(8, b0)  PH(9, b1)  PH(10, b2) PH(11, b3)
    PH(12, b0) PH(13, b1) PH(14, b2) PH(15, b3)
    PH(16, b0) PH(17, b1) PH(18, b2) PH(19, b3)
    PH(20, b0) PH(21, b1)
#undef PH

    // epilogue: dense store + bias
    const int b  = m_base >> 10;
    const int t0 = m_base & 1023;
    {
        const int i  = wave * 16 + col;
        const int c  = i >> 7, df = i & 127;
        const int f  = chunk * CHUNK + df;
        if (f < F_DIM) {
            const float bv = bias_g[c * F_DIM + f];
            float* orow = out + ((size_t)(b * 2 + c) * T_DIM + t0) * F_DIM + f;
#pragma unroll
            for (int mf = 0; mf < 2; ++mf)
#pragma unroll
                for (int reg = 0; reg < 4; ++reg) {
                    const int r = mf * 16 + kg * 4 + reg;
                    orow[(size_t)r * F_DIM] = acc[mf][reg] + bv;
                }
        }
    }
}

extern "C" void kernel_launch(void* const* d_in, const int* in_sizes, int n_in,
                              void* d_out, int out_size, void* d_ws, size_t ws_size,
                              hipStream_t stream) {
    const float* x      = (const float*)d_in[0];
    const float* pre_w  = (const float*)d_in[1];
    const float* pre_b  = (const float*)d_in[2];
    const float* post_w = (const float*)d_in[3];
    const float* post_b = (const float*)d_in[4];
    const int*   idx    = (const int*)d_in[5];
    const float* melw   = (const float*)d_in[6];
    const float* mask   = (const float*)d_in[7];
    const float* ola    = (const float*)d_in[8];
    float* out = (float*)d_out;

    const int W   = in_sizes[5] / K_BANDS;   // <= 112
    const int din = 2 * W;

    // workspace: Mf (banded f32) | bias | preT | postP | Mb
    const size_t mf_bytes   = (size_t)NCHUNK * K2 * OC * 4;          // 6,488,064
    const size_t bias_bytes = 8448;
    float*          Mf     = (float*)d_ws;
    float*          bias_g = (float*)((char*)d_ws + mf_bytes);
    unsigned short* preT   = (unsigned short*)((char*)d_ws + mf_bytes + bias_bytes);
    const size_t frag_bytes = (size_t)K_BANDS * NKTC * NMT * 64 * 8 * 2; // 3,670,016
    unsigned short* postP  = (unsigned short*)((char*)preT + frag_bytes);
    unsigned short* Mb     = (unsigned short*)((char*)postP + frag_bytes);

    const int zcount = (int)((mf_bytes + bias_bytes) / 4);

    bs_prep<<<dim3(K_BANDS, NKTC, 2), 256, 0, stream>>>(
        pre_w, post_w, idx, melw, mask, ola, preT, postP,
        (float*)d_ws, zcount, W, din);
    bs_compose<<<dim3(K_BANDS, NMT + 1), 256, 0, stream>>>(
        preT, postP, pre_b, post_w, post_b, idx, melw, mask, ola,
        Mf, bias_g, W, din);
    bs_mk_bf16<<<dim3(NCHUNK, KT2), 256, 0, stream>>>(Mf, Mb);

    bs_banded<<<dim3((B_DIM * T_DIM) / M_TILE, NCHUNK), 1024, 0, stream>>>(
        x, Mb, bias_g, out);
}